// Round 11
// baseline (403.962 us; speedup 1.0000x reference)
//
#include <hip/hip_runtime.h>
#include <hip/hip_bf16.h>
#include <math.h>

#define NUSER 30000
#define NITEM 30000
#define NN    60000
#define NE    1000000
#define DIMV  64
#define XW    192
#define HIDW  256
#define NB    2048
#define KNB   10
#define MPAD  30080
#define NCH   235      // ceil(NN/256)

typedef __attribute__((ext_vector_type(8))) short bf16x8;
typedef __attribute__((ext_vector_type(4))) float f32x4;

__device__ __forceinline__ short f2bf(float f) {
    union { float f; unsigned u; } v; v.f = f;
    unsigned r = v.u + 0x7fff + ((v.u >> 16) & 1);
    return (short)(r >> 16);
}
__device__ __forceinline__ float bflo(unsigned v) { return __int_as_float(v << 16); }
__device__ __forceinline__ float bfhi(unsigned v) { return __int_as_float(v & 0xffff0000u); }
__device__ __forceinline__ unsigned pack2(float a, float b) {
    return (unsigned)(unsigned short)f2bf(a) | ((unsigned)(unsigned short)f2bf(b) << 16);
}
__device__ __forceinline__ void async16(void* lds, const void* g) {
    __builtin_amdgcn_global_load_lds(
        (const __attribute__((address_space(1))) unsigned*)g,
        (__attribute__((address_space(3))) unsigned*)lds, 16, 0, 0);
}

// ================= degree / CSR =================
__global__ void k_deg(const int* __restrict__ src, unsigned* __restrict__ deg) {
    int e = blockIdx.x * blockDim.x + threadIdx.x;
    if (e < NE) atomicAdd(&deg[src[e]], 1u);
}
__global__ void k_dinv(const unsigned* __restrict__ deg, float* __restrict__ dinv) {
    int i = blockIdx.x * blockDim.x + threadIdx.x;
    if (i < NN) { unsigned d = deg[i]; dinv[i] = d ? rsqrtf((float)d) : 0.f; }
}
__global__ __launch_bounds__(256)
void k_bsum(const unsigned* __restrict__ deg, int* __restrict__ bsum) {
    __shared__ int red[4];
    int g = blockIdx.x * 256 + threadIdx.x;
    int v = (g < NN) ? (int)deg[g] : 0;
    for (int o = 32; o > 0; o >>= 1) v += __shfl_down(v, o);
    int lane = threadIdx.x & 63, wave = threadIdx.x >> 6;
    if (lane == 0) red[wave] = v;
    __syncthreads();
    if (threadIdx.x == 0) bsum[blockIdx.x] = red[0] + red[1] + red[2] + red[3];
}
__global__ __launch_bounds__(256)
void k_bscan(const int* __restrict__ bsum, int* __restrict__ bscan) {
    __shared__ int s[256];
    int t = threadIdx.x;
    int v = (t < NCH) ? bsum[t] : 0;
    s[t] = v;
    __syncthreads();
    for (int o = 1; o < 256; o <<= 1) {
        int u = (t >= o) ? s[t - o] : 0;
        __syncthreads();
        s[t] += u;
        __syncthreads();
    }
    if (t < NCH) bscan[t] = s[t] - v;
}
__global__ __launch_bounds__(256)
void k_rowptr(const unsigned* __restrict__ deg, const int* __restrict__ bscan,
              int* __restrict__ rowptr) {
    __shared__ int s[256];
    int g = blockIdx.x * 256 + threadIdx.x, t = threadIdx.x;
    int v = (g < NN) ? (int)deg[g] : 0;
    s[t] = v;
    __syncthreads();
    for (int o = 1; o < 256; o <<= 1) {
        int u = (t >= o) ? s[t - o] : 0;
        __syncthreads();
        s[t] += u;
        __syncthreads();
    }
    int base = bscan[blockIdx.x];
    if (g < NN) rowptr[g] = base + s[t] - v;
    if (g == NN - 1) rowptr[NN] = base + s[t];
}
__global__ void k_fill(const int* __restrict__ src, const int* __restrict__ dst,
                       const float* __restrict__ dinv, const int* __restrict__ rowptr,
                       unsigned* __restrict__ cursor, int2* __restrict__ csr) {
    int e = blockIdx.x * blockDim.x + threadIdx.x;
    if (e >= NE) return;
    int s = src[e], d = dst[e];
    int pos = (int)atomicAdd(&cursor[d], 1u);
    int2 ew;
    ew.x = s;
    ew.y = __float_as_int(dinv[s] * dinv[d]);
    csr[rowptr[d] + pos] = ew;
}

// ============ fp32 -> bf16 convert (weights only) ============
struct CvtArgs { const float* src[6]; short* dst[6]; };
__constant__ __device__ const int C8PRE[7]  = {0,32768,36864,40960,43008,45056,47104};
__constant__ __device__ const int C8SH[6]   = {7,4,4,5,5,5};
__constant__ __device__ const int C8COLS[6] = {1024,128,100,256,256,256};
__constant__ __device__ const int C8ROWS[6] = {256,256,256,64,64,64};
#define CVT8_TOTAL 47104

__global__ __launch_bounds__(256)
void k_convert(CvtArgs a) {
    int cid = blockIdx.x * 256 + threadIdx.x;
    if (cid >= CVT8_TOTAL) return;
    int j = 0;
    while (cid >= C8PRE[j + 1]) ++j;
    int local = cid - C8PRE[j];
    int sh = C8SH[j];
    int r = local >> sh;
    int col = (local & ((1 << sh) - 1)) * 8;
    int cols = C8COLS[j];
    bf16x8 o = (bf16x8)0;
    if (r < C8ROWS[j]) {
        const float* s = a.src[j] + (size_t)r * cols + col;
        if (col + 8 <= cols) {
            float4 f0 = *(const float4*)s;
            float4 f1 = *(const float4*)(s + 4);
            o[0] = f2bf(f0.x); o[1] = f2bf(f0.y); o[2] = f2bf(f0.z); o[3] = f2bf(f0.w);
            o[4] = f2bf(f1.x); o[5] = f2bf(f1.y); o[6] = f2bf(f1.z); o[7] = f2bf(f1.w);
        } else {
            #pragma unroll
            for (int q = 0; q < 8; ++q)
                if (col + q < cols) o[q] = f2bf(s[q]);
        }
    }
    *(bf16x8*)(a.dst[j] + ((size_t)r << (sh + 3)) + col) = o;
}

// ================= LDS helpers (used by gemm2) =================
__device__ __forceinline__ bf16x8 ldfrag(const short* lds, int row, int kbyte) {
    int off = (row * 128 + kbyte) ^ ((row & 7) << 4);
    return *(const bf16x8*)((const char*)lds + off);
}
#define STAGE_TILE(SMEM, BASEPTR, LDK, ROWOFF, K0, NITERS)                          \
    _Pragma("unroll")                                                                \
    for (int i_ = 0; i_ < (NITERS); ++i_) {                                          \
        int c_ = i_ * 256 + wave * 64 + lane;                                        \
        int r_ = c_ >> 3, slot_ = c_ & 7;                                            \
        int ss_ = slot_ ^ (r_ & 7);                                                  \
        const char* gp_ = (const char*)((BASEPTR) + (size_t)((ROWOFF) + r_) * (LDK)  \
                                        + (K0)) + ss_ * 16;                          \
        async16(&(SMEM)[(i_ * 256 + wave * 64) * 8], gp_);                           \
    }

// ====== GEMM1: NO-LDS direct-fragment MFMA. BM=64 (2 row-waves? no: 2x2 waves), ======
// wave = 32 rows x 128 cols; block = 64 rows x 256 cols; zero barriers.
struct G1Args { const float* A[3]; const short* W[3]; const float* bias[3];
                short* C[3]; int K[3]; int Ksrc[3]; };

__device__ __forceinline__ bf16x8 ldcvtA(const float* ap, int kk, int Ks, bool ok) {
    bf16x8 o;
    if (ok && kk + 8 <= Ks) {
        float4 x = *(const float4*)(ap + kk);
        float4 y = *(const float4*)(ap + kk + 4);
        o[0] = f2bf(x.x); o[1] = f2bf(x.y); o[2] = f2bf(x.z); o[3] = f2bf(x.w);
        o[4] = f2bf(y.x); o[5] = f2bf(y.y); o[6] = f2bf(y.z); o[7] = f2bf(y.w);
    } else {
        #pragma unroll
        for (int j = 0; j < 8; ++j) {
            float v = (ok && kk + j < Ks) ? ap[kk + j] : 0.f;
            o[j] = f2bf(v);
        }
    }
    return o;
}

__global__ __launch_bounds__(256)
void gemm1_mfma(G1Args g) {
    int m = blockIdx.z;
    int K  = g.K[m];          // padded K (stride of W), multiple of 32
    int Ks = g.Ksrc[m];       // true fp32 source cols
    const float* A = g.A[m];
    const short* W = g.W[m];
    int tid = threadIdx.x;
    int lane = tid & 63, wave = tid >> 6;
    int lane15 = lane & 15, lhi = lane >> 4;
    int wrow = wave & 1, wcol = wave >> 1;
    int row0 = blockIdx.x * 64 + wrow * 32;
    int cbase = wcol * 128;
    // A-fragment row pointers (rows row0+lane15, row0+16+lane15)
    int r0 = row0 + lane15, r1 = row0 + 16 + lane15;
    bool ok0 = r0 < NITEM, ok1 = r1 < NITEM;
    const float* ap0 = A + (size_t)(ok0 ? r0 : 0) * Ks;
    const float* ap1 = A + (size_t)(ok1 ? r1 : 0) * Ks;
    // B-fragment base pointer: col = cbase+lane15 (+ni*16), k-offset lhi*8
    const short* bp = W + (size_t)(cbase + lane15) * K + lhi * 8;
    int kA = lhi * 8;
    f32x4 acc[2][8] = {};
    #pragma unroll 4
    for (int k0 = 0; k0 < K; k0 += 32) {
        bf16x8 b[8];
        #pragma unroll
        for (int ni = 0; ni < 8; ++ni)
            b[ni] = *(const bf16x8*)(bp + (size_t)ni * 16 * K + k0);
        int kk = k0 + kA;
        bf16x8 a0 = ldcvtA(ap0, kk, Ks, ok0);
        bf16x8 a1 = ldcvtA(ap1, kk, Ks, ok1);
        #pragma unroll
        for (int ni = 0; ni < 8; ++ni) {
            acc[0][ni] = __builtin_amdgcn_mfma_f32_16x16x32_bf16(a0, b[ni], acc[0][ni], 0, 0, 0);
            acc[1][ni] = __builtin_amdgcn_mfma_f32_16x16x32_bf16(a1, b[ni], acc[1][ni], 0, 0, 0);
        }
    }
    short* C = g.C[m];
    const float* bias = g.bias[m];
    #pragma unroll
    for (int mi = 0; mi < 2; ++mi) {
        int gr0 = row0 + mi * 16 + lhi * 4;
        #pragma unroll
        for (int ni = 0; ni < 8; ++ni) {
            int gcol = cbase + ni * 16 + lane15;
            float bv = bias[gcol];
            #pragma unroll
            for (int r = 0; r < 4; ++r) {
                int grow = gr0 + r;
                if (grow < NITEM) {
                    float v = acc[mi][ni][r] + bv;
                    v = v > 0.f ? v : 0.01f * v;
                    C[(size_t)grow * HIDW + gcol] = f2bf(v);
                }
            }
        }
    }
}

// ================= GEMM2 fused + l2norm =================
struct G2Args { const short* A[3]; const short* W[3]; const float* bias[3]; };
__global__ __launch_bounds__(256)
void gemm2_mfma(G2Args g, float* __restrict__ X, short* __restrict__ Xb) {
    __shared__ __align__(16) short sA[128 * 64];
    __shared__ __align__(16) short sB[64 * 64];
    int m = blockIdx.z;
    const short* A = g.A[m];
    const short* W = g.W[m];
    int lane = threadIdx.x & 63, wave = threadIdx.x >> 6;
    int lane15 = lane & 15, lhi = lane >> 4;
    int row0 = blockIdx.x * 128;
    const int K = HIDW;
    f32x4 acc[2][4] = {};
    for (int t = 0; t < 4; ++t) {
        int k0 = t * 64;
        STAGE_TILE(sA, A, K, row0, k0, 4)
        STAGE_TILE(sB, W, K, 0, k0, 2)
        __syncthreads();
        #pragma unroll
        for (int ks = 0; ks < 2; ++ks) {
            int kb = ks * 64 + lhi * 16;
            bf16x8 a[2], b[4];
            #pragma unroll
            for (int mi = 0; mi < 2; ++mi) a[mi] = ldfrag(sA, wave * 32 + mi * 16 + lane15, kb);
            #pragma unroll
            for (int ni = 0; ni < 4; ++ni) b[ni] = ldfrag(sB, ni * 16 + lane15, kb);
            #pragma unroll
            for (int mi = 0; mi < 2; ++mi)
                #pragma unroll
                for (int ni = 0; ni < 4; ++ni)
                    acc[mi][ni] = __builtin_amdgcn_mfma_f32_16x16x32_bf16(a[mi], b[ni], acc[mi][ni], 0, 0, 0);
        }
        __syncthreads();
    }
    const float* bias = g.bias[m];
    #pragma unroll
    for (int mi = 0; mi < 2; ++mi) {
        float v[4][4];
        float sumsq[4] = {};
        #pragma unroll
        for (int ni = 0; ni < 4; ++ni) {
            float bv = bias[ni * 16 + lane15];
            #pragma unroll
            for (int r = 0; r < 4; ++r) {
                float x = acc[mi][ni][r] + bv;
                v[ni][r] = x;
                sumsq[r] += x * x;
            }
        }
        #pragma unroll
        for (int r = 0; r < 4; ++r) {
            float s = sumsq[r];
            s += __shfl_xor(s, 1); s += __shfl_xor(s, 2);
            s += __shfl_xor(s, 4); s += __shfl_xor(s, 8);
            sumsq[r] = 1.f / fmaxf(sqrtf(s), 1e-12f);
        }
        int grow0 = row0 + wave * 32 + mi * 16 + lhi * 4;
        #pragma unroll
        for (int r = 0; r < 4; ++r) {
            int grow = grow0 + r;
            if (grow < NITEM) {
                float sc = sumsq[r];
                size_t o = (size_t)(NUSER + grow) * XW + m * DIMV;
                #pragma unroll
                for (int ni = 0; ni < 4; ++ni) {
                    float val = v[ni][r] * sc;
                    X[o + ni * 16 + lane15] = val;
                    Xb[o + ni * 16 + lane15] = f2bf(val);
                }
            }
        }
    }
}

// ================= user rows =================
__global__ void k_users_norm(const float* __restrict__ vp, const float* __restrict__ ap,
                             const float* __restrict__ tp, float* __restrict__ X,
                             short* __restrict__ Xb) {
    int gw = (blockIdx.x * blockDim.x + threadIdx.x) >> 6;
    int lane = threadIdx.x & 63;
    if (gw >= NUSER * 3) return;
    int u = gw / 3, m = gw % 3;
    const float* p = (m == 0) ? vp : (m == 1) ? ap : tp;
    float v = p[(size_t)u * DIMV + lane];
    float s = v * v;
    for (int o = 32; o > 0; o >>= 1) s += __shfl_xor(s, o);
    float sc = 1.f / fmaxf(sqrtf(s), 1e-12f);
    size_t o = (size_t)u * XW + m * DIMV + lane;
    float val = v * sc;
    X[o] = val;
    Xb[o] = f2bf(val);
}

// ================= gather SpMM, readlane SGPR bases =================
template<int MODE>
__global__ __launch_bounds__(256)
void k_spmm(const int* __restrict__ rowptr, const int2* __restrict__ csr,
            const short* __restrict__ INB, const float* __restrict__ Xf,
            float* __restrict__ OUTf, short* __restrict__ OUTB) {
    int n = blockIdx.x * 4 + (threadIdx.x >> 6);
    int l = threadIdx.x & 63;
    if (n >= NN) return;
    int lo = rowptr[n], hi = rowptr[n + 1];
    int lc = l < 48 ? l : 47;
    float f0 = 0.f, f1 = 0.f, f2 = 0.f, f3 = 0.f;
    for (int base = lo; base < hi; base += 64) {
        int idx = base + l;
        int2 e = (idx < hi) ? csr[idx] : make_int2(0, 0);
        int m = hi - base; if (m > 64) m = 64;
        int j = 0;
        for (; j + 4 <= m; j += 4) {
            int s0 = __builtin_amdgcn_readlane(e.x, j + 0);
            int s1 = __builtin_amdgcn_readlane(e.x, j + 1);
            int s2 = __builtin_amdgcn_readlane(e.x, j + 2);
            int s3 = __builtin_amdgcn_readlane(e.x, j + 3);
            float w0 = __int_as_float(__builtin_amdgcn_readlane(e.y, j + 0));
            float w1 = __int_as_float(__builtin_amdgcn_readlane(e.y, j + 1));
            float w2 = __int_as_float(__builtin_amdgcn_readlane(e.y, j + 2));
            float w3 = __int_as_float(__builtin_amdgcn_readlane(e.y, j + 3));
            uint2 v0 = ((const uint2*)(INB + (size_t)s0 * XW))[lc];
            uint2 v1 = ((const uint2*)(INB + (size_t)s1 * XW))[lc];
            uint2 v2 = ((const uint2*)(INB + (size_t)s2 * XW))[lc];
            uint2 v3 = ((const uint2*)(INB + (size_t)s3 * XW))[lc];
            f0 += w0 * bflo(v0.x); f1 += w0 * bfhi(v0.x);
            f2 += w0 * bflo(v0.y); f3 += w0 * bfhi(v0.y);
            f0 += w1 * bflo(v1.x); f1 += w1 * bfhi(v1.x);
            f2 += w1 * bflo(v1.y); f3 += w1 * bfhi(v1.y);
            f0 += w2 * bflo(v2.x); f1 += w2 * bfhi(v2.x);
            f2 += w2 * bflo(v2.y); f3 += w2 * bfhi(v2.y);
            f0 += w3 * bflo(v3.x); f1 += w3 * bfhi(v3.x);
            f2 += w3 * bflo(v3.y); f3 += w3 * bfhi(v3.y);
        }
        for (; j < m; ++j) {
            int s0 = __builtin_amdgcn_readlane(e.x, j);
            float w0 = __int_as_float(__builtin_amdgcn_readlane(e.y, j));
            uint2 v0 = ((const uint2*)(INB + (size_t)s0 * XW))[lc];
            f0 += w0 * bflo(v0.x); f1 += w0 * bfhi(v0.x);
            f2 += w0 * bflo(v0.y); f3 += w0 * bfhi(v0.y);
        }
    }
    if (MODE == 1) {
        float4 xv = ((const float4*)(Xf + (size_t)n * XW))[lc];
        uint2 hb = ((const uint2*)(INB + (size_t)n * XW))[lc];
        f0 += xv.x + bflo(hb.x); f1 += xv.y + bfhi(hb.x);
        f2 += xv.z + bflo(hb.y); f3 += xv.w + bfhi(hb.y);
    }
    if (l < 48) {
        if (MODE == 0) {
            uint2 ob;
            ob.x = pack2(f0, f1);
            ob.y = pack2(f2, f3);
            ((uint2*)(OUTB + (size_t)n * XW))[l] = ob;
        } else {
            ((float4*)(OUTf + (size_t)n * XW))[l] = make_float4(f0, f1, f2, f3);
        }
    }
}

// ================= combine / usergraph / scores =================
__global__ void k_combine(const float* __restrict__ REP, const float* __restrict__ wu,
                          float* __restrict__ UR, float* __restrict__ RES) {
    int t = blockIdx.x * blockDim.x + threadIdx.x;
    if (t >= NN * DIMV) return;
    int n = t >> 6, d = t & 63;
    const float* r = REP + (size_t)n * XW;
    float r0 = r[d], r1 = r[DIMV + d], r2 = r[2 * DIMV + d];
    if (n < NUSER) {
        float w0 = wu[n * 3 + 0], w1 = wu[n * 3 + 1], w2 = wu[n * 3 + 2];
        UR[(size_t)n * DIMV + d] = r0 * w0 + r1 * w1 + r2 * w2;
    } else {
        RES[(size_t)n * DIMV + d] = (r0 + r1 + r2) * (1.f / 3.f);
    }
}
__global__ void k_usergraph(const float* __restrict__ UR, const int* __restrict__ g,
                            const float* __restrict__ w, float* __restrict__ RES) {
    int t = blockIdx.x * blockDim.x + threadIdx.x;
    if (t >= NUSER * DIMV) return;
    int n = t >> 6, d = t & 63;
    float acc = UR[(size_t)n * DIMV + d];
    for (int k = 0; k < KNB; ++k) {
        int nb = g[n * KNB + k];
        acc += w[n * KNB + k] * UR[(size_t)nb * DIMV + d];
    }
    RES[(size_t)n * DIMV + d] = acc;
}
__global__ void k_scores(const float* __restrict__ RES, const int* __restrict__ un,
                         const int* __restrict__ pn, const int* __restrict__ nn,
                         float* __restrict__ out) {
    int gw = (blockIdx.x * blockDim.x + threadIdx.x) >> 6;
    int lane = threadIdx.x & 63;
    if (gw >= NB) return;
    int u = un[gw], p = pn[gw], ng = nn[gw];
    float uv = RES[(size_t)u * DIMV + lane];
    float ps = uv * RES[(size_t)p * DIMV + lane];
    float ns = uv * RES[(size_t)ng * DIMV + lane];
    for (int o = 32; o > 0; o >>= 1) {
        ps += __shfl_xor(ps, o);
        ns += __shfl_xor(ns, o);
    }
    if (lane == 0) { out[gw] = ps; out[NB + gw] = ns; }
}

extern "C" void kernel_launch(void* const* d_in, const int* in_sizes, int n_in,
                              void* d_out, int out_size, void* d_ws, size_t ws_size,
                              hipStream_t stream) {
    const int*   un    = (const int*)d_in[0];
    const int*   pn    = (const int*)d_in[1];
    const int*   ngn   = (const int*)d_in[2];
    const int*   ug    = (const int*)d_in[3];
    const int*   eidx  = (const int*)d_in[4];
    const float* uwm   = (const float*)d_in[5];
    const float* feats[3] = { (const float*)d_in[6], (const float*)d_in[7], (const float*)d_in[8] };
    const float* prefs[3] = { (const float*)d_in[9], (const float*)d_in[10], (const float*)d_in[11] };
    const float* W1[3] = { (const float*)d_in[12], (const float*)d_in[16], (const float*)d_in[20] };
    const float* b1[3] = { (const float*)d_in[13], (const float*)d_in[17], (const float*)d_in[21] };
    const float* W2[3] = { (const float*)d_in[14], (const float*)d_in[18], (const float*)d_in[22] };
    const float* b2[3] = { (const float*)d_in[15], (const float*)d_in[19], (const float*)d_in[23] };
    const float* wu    = (const float*)d_in[24];
    float* out = (float*)d_out;

    const int* esrc = eidx;
    const int* edst = eidx + NE;

    // ---- workspace ----
    char* ws = (char*)d_ws;
    size_t off = 0;
    auto alloc = [&](size_t bytes) { void* p = ws + off; off = (off + bytes + 255) & ~(size_t)255; return p; };
    unsigned* deg    = (unsigned*)alloc(NN * 4);
    float*    dinv   = (float*)alloc(NN * 4);
    int*      rowptr = (int*)alloc((NN + 1) * 4);
    int*      bsum   = (int*)alloc(NCH * 4);
    int*      bscan  = (int*)alloc(NCH * 4);
    int2*     csr    = (int2*)alloc((size_t)NE * 8);
    float*    X      = (float*)alloc((size_t)NN * XW * 4);
    short*    Xb     = (short*)alloc((size_t)NN * XW * 2);
    char* region2 = (char*)alloc((size_t)3 * MPAD * HIDW * 2);
    short* hid[3] = { (short*)region2,
                      (short*)(region2 + (size_t)MPAD * HIDW * 2),
                      (short*)(region2 + (size_t)2 * MPAD * HIDW * 2) };
    float* RES = (float*)region2;
    float* UR  = (float*)(region2 + (size_t)NN * DIMV * 4 + 40960);
    short* Hb  = (short*)(region2 + (size_t)NN * DIMV * 4 + 40960 + (size_t)NUSER * DIMV * 4);
    short* w1b = (short*)alloc((size_t)256 * 1280 * 2);
    short* w1s[3] = { w1b, w1b + 256 * 1024, w1b + 256 * (1024 + 128) };
    short* w2b = (short*)alloc((size_t)3 * 64 * HIDW * 2);
    short* w2s[3] = { w2b, w2b + 64 * HIDW, w2b + 2 * 64 * HIDW };

    // ---- 1. convert weights fp32->bf16 (tiny) ----
    CvtArgs ca;
    ca.src[0] = W1[0]; ca.src[1] = W1[1]; ca.src[2] = W1[2];
    ca.src[3] = W2[0]; ca.src[4] = W2[1]; ca.src[5] = W2[2];
    ca.dst[0] = w1s[0]; ca.dst[1] = w1s[1]; ca.dst[2] = w1s[2];
    ca.dst[3] = w2s[0]; ca.dst[4] = w2s[1]; ca.dst[5] = w2s[2];
    k_convert<<<(CVT8_TOTAL + 255) / 256, 256, 0, stream>>>(ca);

    // ---- 2. CSR build ----
    hipMemsetAsync(deg, 0, NN * 4, stream);
    k_deg<<<(NE + 255) / 256, 256, 0, stream>>>(esrc, deg);
    k_dinv<<<(NN + 255) / 256, 256, 0, stream>>>(deg, dinv);
    k_bsum<<<NCH, 256, 0, stream>>>(deg, bsum);
    k_bscan<<<1, 256, 0, stream>>>(bsum, bscan);
    k_rowptr<<<NCH, 256, 0, stream>>>(deg, bscan, rowptr);
    hipMemsetAsync(deg, 0, NN * 4, stream);
    k_fill<<<(NE + 255) / 256, 256, 0, stream>>>(esrc, edst, dinv, rowptr, deg, csr);

    // ---- 3. gemm1 fused (no-LDS direct-fragment MFMA, zero barriers) ----
    G1Args g1;
    for (int m = 0; m < 3; ++m) { g1.bias[m] = b1[m]; g1.C[m] = hid[m]; g1.W[m] = w1s[m]; g1.A[m] = feats[m]; }
    g1.K[0] = 1024; g1.K[1] = 128; g1.K[2] = 128;
    g1.Ksrc[0] = 1024; g1.Ksrc[1] = 128; g1.Ksrc[2] = 100;
    gemm1_mfma<<<dim3(MPAD / 64, 1, 3), 256, 0, stream>>>(g1);

    // ---- 4. gemm2 fused ----
    G2Args g2;
    for (int m = 0; m < 3; ++m) { g2.A[m] = hid[m]; g2.W[m] = w2s[m]; g2.bias[m] = b2[m]; }
    gemm2_mfma<<<dim3(MPAD / 128, 1, 3), 256, 0, stream>>>(g2, X, Xb);
    k_users_norm<<<(NUSER * 3 * 64 + 255) / 256, 256, 0, stream>>>(prefs[0], prefs[1], prefs[2], X, Xb);

    // ---- 5. conv1: Hb = bf16(A * X) ----
    k_spmm<0><<<(NN + 3) / 4, 256, 0, stream>>>(rowptr, csr, Xb, nullptr, nullptr, Hb);

    // ---- 6. conv2: X(=REP) = X + Hb + A * Hb ----
    k_spmm<1><<<(NN + 3) / 4, 256, 0, stream>>>(rowptr, csr, Hb, X, X, nullptr);

    // ---- 7. combine / usergraph / scores ----
    k_combine<<<(NN * DIMV + 255) / 256, 256, 0, stream>>>(X, wu, UR, RES);
    k_usergraph<<<(NUSER * DIMV + 255) / 256, 256, 0, stream>>>(UR, ug, uwm, RES);
    k_scores<<<(NB * 64 + 255) / 256, 256, 0, stream>>>(RES, un, pn, ngn, out);
}

// Round 12
// 341.854 us; speedup vs baseline: 1.1817x; 1.1817x over previous
//
#include <hip/hip_runtime.h>
#include <hip/hip_bf16.h>
#include <math.h>

#define NUSER 30000
#define NITEM 30000
#define NN    60000
#define NE    1000000
#define DIMV  64
#define XW    192
#define HIDW  256
#define NB    2048
#define KNB   10
#define MPAD  30080
#define NCH   235      // ceil(NN/256)

typedef __attribute__((ext_vector_type(8))) short bf16x8;
typedef __attribute__((ext_vector_type(4))) float f32x4;

__device__ __forceinline__ short f2bf(float f) {
    union { float f; unsigned u; } v; v.f = f;
    unsigned r = v.u + 0x7fff + ((v.u >> 16) & 1);
    return (short)(r >> 16);
}
__device__ __forceinline__ float bflo(unsigned v) { return __int_as_float(v << 16); }
__device__ __forceinline__ float bfhi(unsigned v) { return __int_as_float(v & 0xffff0000u); }
__device__ __forceinline__ unsigned pack2(float a, float b) {
    return (unsigned)(unsigned short)f2bf(a) | ((unsigned)(unsigned short)f2bf(b) << 16);
}
__device__ __forceinline__ void async16(void* lds, const void* g) {
    __builtin_amdgcn_global_load_lds(
        (const __attribute__((address_space(1))) unsigned*)g,
        (__attribute__((address_space(3))) unsigned*)lds, 16, 0, 0);
}

// ================= degree / CSR =================
__global__ void k_deg(const int* __restrict__ src, unsigned* __restrict__ deg) {
    int e = blockIdx.x * blockDim.x + threadIdx.x;
    if (e < NE) atomicAdd(&deg[src[e]], 1u);
}
__global__ void k_dinv(const unsigned* __restrict__ deg, float* __restrict__ dinv) {
    int i = blockIdx.x * blockDim.x + threadIdx.x;
    if (i < NN) { unsigned d = deg[i]; dinv[i] = d ? rsqrtf((float)d) : 0.f; }
}
__global__ __launch_bounds__(256)
void k_bsum(const unsigned* __restrict__ deg, int* __restrict__ bsum) {
    __shared__ int red[4];
    int g = blockIdx.x * 256 + threadIdx.x;
    int v = (g < NN) ? (int)deg[g] : 0;
    for (int o = 32; o > 0; o >>= 1) v += __shfl_down(v, o);
    int lane = threadIdx.x & 63, wave = threadIdx.x >> 6;
    if (lane == 0) red[wave] = v;
    __syncthreads();
    if (threadIdx.x == 0) bsum[blockIdx.x] = red[0] + red[1] + red[2] + red[3];
}
__global__ __launch_bounds__(256)
void k_bscan(const int* __restrict__ bsum, int* __restrict__ bscan) {
    __shared__ int s[256];
    int t = threadIdx.x;
    int v = (t < NCH) ? bsum[t] : 0;
    s[t] = v;
    __syncthreads();
    for (int o = 1; o < 256; o <<= 1) {
        int u = (t >= o) ? s[t - o] : 0;
        __syncthreads();
        s[t] += u;
        __syncthreads();
    }
    if (t < NCH) bscan[t] = s[t] - v;
}
__global__ __launch_bounds__(256)
void k_rowptr(const unsigned* __restrict__ deg, const int* __restrict__ bscan,
              int* __restrict__ rowptr) {
    __shared__ int s[256];
    int g = blockIdx.x * 256 + threadIdx.x, t = threadIdx.x;
    int v = (g < NN) ? (int)deg[g] : 0;
    s[t] = v;
    __syncthreads();
    for (int o = 1; o < 256; o <<= 1) {
        int u = (t >= o) ? s[t - o] : 0;
        __syncthreads();
        s[t] += u;
        __syncthreads();
    }
    int base = bscan[blockIdx.x];
    if (g < NN) rowptr[g] = base + s[t] - v;
    if (g == NN - 1) rowptr[NN] = base + s[t];
}
__global__ void k_fill(const int* __restrict__ src, const int* __restrict__ dst,
                       const float* __restrict__ dinv, const int* __restrict__ rowptr,
                       unsigned* __restrict__ cursor, int2* __restrict__ csr) {
    int e = blockIdx.x * blockDim.x + threadIdx.x;
    if (e >= NE) return;
    int s = src[e], d = dst[e];
    int pos = (int)atomicAdd(&cursor[d], 1u);
    int2 ew;
    ew.x = s;
    ew.y = __float_as_int(dinv[s] * dinv[d]);
    csr[rowptr[d] + pos] = ew;
}

// ============ fp32 -> bf16 convert (weights only) ============
struct CvtArgs { const float* src[6]; short* dst[6]; };
__constant__ __device__ const int C8PRE[7]  = {0,32768,36864,40960,43008,45056,47104};
__constant__ __device__ const int C8SH[6]   = {7,4,4,5,5,5};
__constant__ __device__ const int C8COLS[6] = {1024,128,100,256,256,256};
__constant__ __device__ const int C8ROWS[6] = {256,256,256,64,64,64};
#define CVT8_TOTAL 47104

__global__ __launch_bounds__(256)
void k_convert(CvtArgs a) {
    int cid = blockIdx.x * 256 + threadIdx.x;
    if (cid >= CVT8_TOTAL) return;
    int j = 0;
    while (cid >= C8PRE[j + 1]) ++j;
    int local = cid - C8PRE[j];
    int sh = C8SH[j];
    int r = local >> sh;
    int col = (local & ((1 << sh) - 1)) * 8;
    int cols = C8COLS[j];
    bf16x8 o = (bf16x8)0;
    if (r < C8ROWS[j]) {
        const float* s = a.src[j] + (size_t)r * cols + col;
        if (col + 8 <= cols) {
            float4 f0 = *(const float4*)s;
            float4 f1 = *(const float4*)(s + 4);
            o[0] = f2bf(f0.x); o[1] = f2bf(f0.y); o[2] = f2bf(f0.z); o[3] = f2bf(f0.w);
            o[4] = f2bf(f1.x); o[5] = f2bf(f1.y); o[6] = f2bf(f1.z); o[7] = f2bf(f1.w);
        } else {
            #pragma unroll
            for (int q = 0; q < 8; ++q)
                if (col + q < cols) o[q] = f2bf(s[q]);
        }
    }
    *(bf16x8*)(a.dst[j] + ((size_t)r << (sh + 3)) + col) = o;
}

// ================= LDS helpers =================
__device__ __forceinline__ bf16x8 ldfrag(const short* lds, int row, int kbyte) {
    int off = (row * 128 + kbyte) ^ ((row & 7) << 4);
    return *(const bf16x8*)((const char*)lds + off);
}
// 512B-row-stride variant (for the 64x256 hidden tile)
__device__ __forceinline__ bf16x8 ldfrag512(const short* lds, int row, int kbyte) {
    int off = (row * 512 + kbyte) ^ ((row & 7) << 4);
    return *(const bf16x8*)((const char*)lds + off);
}
#define STAGE_TILE(SMEM, BASEPTR, LDK, ROWOFF, K0, NITERS)                          \
    _Pragma("unroll")                                                                \
    for (int i_ = 0; i_ < (NITERS); ++i_) {                                          \
        int c_ = i_ * 256 + wave * 64 + lane;                                        \
        int r_ = c_ >> 3, slot_ = c_ & 7;                                            \
        int ss_ = slot_ ^ (r_ & 7);                                                  \
        const char* gp_ = (const char*)((BASEPTR) + (size_t)((ROWOFF) + r_) * (LDK)  \
                                        + (K0)) + ss_ * 16;                          \
        async16(&(SMEM)[(i_ * 256 + wave * 64) * 8], gp_);                           \
    }

// ====== FUSED GEMM12: BM=64, BN=256(full). Phase1: lrelu(A*W1^T+b1) -> LDS.
//        Phase2: hidden*W2^T + b2 -> l2norm -> X/Xb. One kernel, no hidden roundtrip.
struct G12Args { const float* A[3]; const short* W1[3]; const float* b1[3];
                 const short* W2[3]; const float* b2[3]; int K[3]; int Ksrc[3]; };
__global__ __launch_bounds__(256)
void gemm12_mfma(G12Args g, float* __restrict__ X, short* __restrict__ Xb) {
    __shared__ __align__(16) short sA[64 * 64];        // 8 KB
    __shared__ __align__(16) short sB[256 * 64];       // 32 KB; reused as 64x256 hidden
    short* sHid = sB;
    int m = blockIdx.z;
    int K  = g.K[m];
    int Ks = g.Ksrc[m];
    const float* A  = g.A[m];
    const short* W1 = g.W1[m];
    int tid = threadIdx.x;
    int lane = tid & 63, wave = tid >> 6;
    int wr = wave >> 1, wc = wave & 1;                 // phase1: 2x2 waves, 32 rows x 128 cols
    int lane15 = lane & 15, lhi = lane >> 4;
    int row0 = blockIdx.x * 64;
    int srow = tid >> 2, sc16 = tid & 3;
    int grow_s = row0 + srow;
    bool rowok = grow_s < NITEM;
    const float* arow = A + (size_t)grow_s * Ks + sc16 * 16;
    int nt = K >> 6;
    float4 f[4];
    auto loadA = [&](int t) {
        int k0 = t * 64;
        int gk = k0 + sc16 * 16;
        if (rowok && gk + 16 <= Ks) {
            #pragma unroll
            for (int q = 0; q < 4; ++q) f[q] = *(const float4*)(arow + k0 + q * 4);
        } else {
            #pragma unroll
            for (int q = 0; q < 4; ++q) {
                float4 z = make_float4(0.f, 0.f, 0.f, 0.f);
                if (rowok) {
                    int c = gk + q * 4;
                    if (c + 4 <= Ks) {
                        z = *(const float4*)(arow + k0 + q * 4);
                    } else {
                        if (c + 0 < Ks) z.x = arow[k0 + q * 4 + 0];
                        if (c + 1 < Ks) z.y = arow[k0 + q * 4 + 1];
                        if (c + 2 < Ks) z.z = arow[k0 + q * 4 + 2];
                        if (c + 3 < Ks) z.w = arow[k0 + q * 4 + 3];
                    }
                }
                f[q] = z;
            }
        }
    };
    loadA(0);
    f32x4 acc[2][8] = {};
    for (int t = 0; t < nt; ++t) {
        #pragma unroll
        for (int q = 0; q < 2; ++q) {
            bf16x8 o;
            float4 lo = f[q * 2], hi = f[q * 2 + 1];
            o[0] = f2bf(lo.x); o[1] = f2bf(lo.y); o[2] = f2bf(lo.z); o[3] = f2bf(lo.w);
            o[4] = f2bf(hi.x); o[5] = f2bf(hi.y); o[6] = f2bf(hi.z); o[7] = f2bf(hi.w);
            int c8 = sc16 * 2 + q;
            int off = (srow * 128 + c8 * 16) ^ ((srow & 7) << 4);
            *(bf16x8*)((char*)sA + off) = o;
        }
        STAGE_TILE(sB, W1, K, 0, t * 64, 8)
        __syncthreads();
        if (t + 1 < nt) loadA(t + 1);    // prefetch next A tile; overlaps MFMA
        #pragma unroll
        for (int ks = 0; ks < 2; ++ks) {
            int kb = ks * 64 + lhi * 16;
            bf16x8 a[2], b[8];
            #pragma unroll
            for (int mi = 0; mi < 2; ++mi) a[mi] = ldfrag(sA, wr * 32 + mi * 16 + lane15, kb);
            #pragma unroll
            for (int ni = 0; ni < 8; ++ni) b[ni] = ldfrag(sB, wc * 128 + ni * 16 + lane15, kb);
            #pragma unroll
            for (int mi = 0; mi < 2; ++mi)
                #pragma unroll
                for (int ni = 0; ni < 8; ++ni)
                    acc[mi][ni] = __builtin_amdgcn_mfma_f32_16x16x32_bf16(a[mi], b[ni], acc[mi][ni], 0, 0, 0);
        }
        __syncthreads();
    }
    // ---- bridge: bias1 + lrelu -> bf16 -> sHid (64 x 256, 512B row stride, swizzled) ----
    const float* b1 = g.b1[m];
    #pragma unroll
    for (int mi = 0; mi < 2; ++mi) {
        int rh0 = wr * 32 + mi * 16 + lhi * 4;
        #pragma unroll
        for (int ni = 0; ni < 8; ++ni) {
            int ch = wc * 128 + ni * 16 + lane15;
            float bv = b1[ch];
            #pragma unroll
            for (int r = 0; r < 4; ++r) {
                float v = acc[mi][ni][r] + bv;
                v = v > 0.f ? v : 0.01f * v;
                int rh = rh0 + r;
                int off = (rh * 512 + ch * 2) ^ ((rh & 7) << 4);
                *(short*)((char*)sHid + off) = f2bf(v);
            }
        }
    }
    __syncthreads();
    // ---- phase2: out(64x64) = hidden(64x256) * W2^T(64x256); wave owns 16 rows x 64 cols ----
    const short* W2 = g.W2[m];
    const short* bp2 = W2 + (size_t)lane15 * HIDW + lhi * 8;   // + ni*16*HIDW + k0
    f32x4 acc2[4] = {};
    #pragma unroll
    for (int k0 = 0; k0 < HIDW; k0 += 32) {
        bf16x8 a2 = ldfrag512(sHid, wave * 16 + lane15, k0 * 2 + lhi * 16);
        #pragma unroll
        for (int ni = 0; ni < 4; ++ni) {
            bf16x8 b2 = *(const bf16x8*)(bp2 + (size_t)ni * 16 * HIDW + k0);
            acc2[ni] = __builtin_amdgcn_mfma_f32_16x16x32_bf16(a2, b2, acc2[ni], 0, 0, 0);
        }
    }
    // ---- bias2 + row l2norm -> X fp32 + Xb bf16 ----
    const float* b2 = g.b2[m];
    float v2[4][4];
    float sumsq[4] = {};
    #pragma unroll
    for (int ni = 0; ni < 4; ++ni) {
        float bv = b2[ni * 16 + lane15];
        #pragma unroll
        for (int r = 0; r < 4; ++r) {
            float x = acc2[ni][r] + bv;
            v2[ni][r] = x;
            sumsq[r] += x * x;
        }
    }
    #pragma unroll
    for (int r = 0; r < 4; ++r) {
        float s = sumsq[r];
        s += __shfl_xor(s, 1); s += __shfl_xor(s, 2);
        s += __shfl_xor(s, 4); s += __shfl_xor(s, 8);
        sumsq[r] = 1.f / fmaxf(sqrtf(s), 1e-12f);
    }
    int grow0 = row0 + wave * 16 + lhi * 4;
    #pragma unroll
    for (int r = 0; r < 4; ++r) {
        int grow = grow0 + r;
        if (grow < NITEM) {
            float sc = sumsq[r];
            size_t o = (size_t)(NUSER + grow) * XW + m * DIMV;
            #pragma unroll
            for (int ni = 0; ni < 4; ++ni) {
                float val = v2[ni][r] * sc;
                X[o + ni * 16 + lane15] = val;
                Xb[o + ni * 16 + lane15] = f2bf(val);
            }
        }
    }
}

// ================= user rows =================
__global__ void k_users_norm(const float* __restrict__ vp, const float* __restrict__ ap,
                             const float* __restrict__ tp, float* __restrict__ X,
                             short* __restrict__ Xb) {
    int gw = (blockIdx.x * blockDim.x + threadIdx.x) >> 6;
    int lane = threadIdx.x & 63;
    if (gw >= NUSER * 3) return;
    int u = gw / 3, m = gw % 3;
    const float* p = (m == 0) ? vp : (m == 1) ? ap : tp;
    float v = p[(size_t)u * DIMV + lane];
    float s = v * v;
    for (int o = 32; o > 0; o >>= 1) s += __shfl_xor(s, o);
    float sc = 1.f / fmaxf(sqrtf(s), 1e-12f);
    size_t o = (size_t)u * XW + m * DIMV + lane;
    float val = v * sc;
    X[o] = val;
    Xb[o] = f2bf(val);
}

// ================= gather SpMM, readlane SGPR bases =================
template<int MODE>
__global__ __launch_bounds__(256)
void k_spmm(const int* __restrict__ rowptr, const int2* __restrict__ csr,
            const short* __restrict__ INB, const float* __restrict__ Xf,
            float* __restrict__ OUTf, short* __restrict__ OUTB) {
    int n = blockIdx.x * 4 + (threadIdx.x >> 6);
    int l = threadIdx.x & 63;
    if (n >= NN) return;
    int lo = rowptr[n], hi = rowptr[n + 1];
    int lc = l < 48 ? l : 47;
    float f0 = 0.f, f1 = 0.f, f2 = 0.f, f3 = 0.f;
    for (int base = lo; base < hi; base += 64) {
        int idx = base + l;
        int2 e = (idx < hi) ? csr[idx] : make_int2(0, 0);
        int m = hi - base; if (m > 64) m = 64;
        int j = 0;
        for (; j + 4 <= m; j += 4) {
            int s0 = __builtin_amdgcn_readlane(e.x, j + 0);
            int s1 = __builtin_amdgcn_readlane(e.x, j + 1);
            int s2 = __builtin_amdgcn_readlane(e.x, j + 2);
            int s3 = __builtin_amdgcn_readlane(e.x, j + 3);
            float w0 = __int_as_float(__builtin_amdgcn_readlane(e.y, j + 0));
            float w1 = __int_as_float(__builtin_amdgcn_readlane(e.y, j + 1));
            float w2 = __int_as_float(__builtin_amdgcn_readlane(e.y, j + 2));
            float w3 = __int_as_float(__builtin_amdgcn_readlane(e.y, j + 3));
            uint2 v0 = ((const uint2*)(INB + (size_t)s0 * XW))[lc];
            uint2 v1 = ((const uint2*)(INB + (size_t)s1 * XW))[lc];
            uint2 v2 = ((const uint2*)(INB + (size_t)s2 * XW))[lc];
            uint2 v3 = ((const uint2*)(INB + (size_t)s3 * XW))[lc];
            f0 += w0 * bflo(v0.x); f1 += w0 * bfhi(v0.x);
            f2 += w0 * bflo(v0.y); f3 += w0 * bfhi(v0.y);
            f0 += w1 * bflo(v1.x); f1 += w1 * bfhi(v1.x);
            f2 += w1 * bflo(v1.y); f3 += w1 * bfhi(v1.y);
            f0 += w2 * bflo(v2.x); f1 += w2 * bfhi(v2.x);
            f2 += w2 * bflo(v2.y); f3 += w2 * bfhi(v2.y);
            f0 += w3 * bflo(v3.x); f1 += w3 * bfhi(v3.x);
            f2 += w3 * bflo(v3.y); f3 += w3 * bfhi(v3.y);
        }
        for (; j < m; ++j) {
            int s0 = __builtin_amdgcn_readlane(e.x, j);
            float w0 = __int_as_float(__builtin_amdgcn_readlane(e.y, j));
            uint2 v0 = ((const uint2*)(INB + (size_t)s0 * XW))[lc];
            f0 += w0 * bflo(v0.x); f1 += w0 * bfhi(v0.x);
            f2 += w0 * bflo(v0.y); f3 += w0 * bfhi(v0.y);
        }
    }
    if (MODE == 1) {
        float4 xv = ((const float4*)(Xf + (size_t)n * XW))[lc];
        uint2 hb = ((const uint2*)(INB + (size_t)n * XW))[lc];
        f0 += xv.x + bflo(hb.x); f1 += xv.y + bfhi(hb.x);
        f2 += xv.z + bflo(hb.y); f3 += xv.w + bfhi(hb.y);
    }
    if (l < 48) {
        if (MODE == 0) {
            uint2 ob;
            ob.x = pack2(f0, f1);
            ob.y = pack2(f2, f3);
            ((uint2*)(OUTB + (size_t)n * XW))[l] = ob;
        } else {
            ((float4*)(OUTf + (size_t)n * XW))[l] = make_float4(f0, f1, f2, f3);
        }
    }
}

// ================= combine / usergraph / scores =================
__global__ void k_combine(const float* __restrict__ REP, const float* __restrict__ wu,
                          float* __restrict__ UR, float* __restrict__ RES) {
    int t = blockIdx.x * blockDim.x + threadIdx.x;
    if (t >= NN * DIMV) return;
    int n = t >> 6, d = t & 63;
    const float* r = REP + (size_t)n * XW;
    float r0 = r[d], r1 = r[DIMV + d], r2 = r[2 * DIMV + d];
    if (n < NUSER) {
        float w0 = wu[n * 3 + 0], w1 = wu[n * 3 + 1], w2 = wu[n * 3 + 2];
        UR[(size_t)n * DIMV + d] = r0 * w0 + r1 * w1 + r2 * w2;
    } else {
        RES[(size_t)n * DIMV + d] = (r0 + r1 + r2) * (1.f / 3.f);
    }
}
__global__ void k_usergraph(const float* __restrict__ UR, const int* __restrict__ g,
                            const float* __restrict__ w, float* __restrict__ RES) {
    int t = blockIdx.x * blockDim.x + threadIdx.x;
    if (t >= NUSER * DIMV) return;
    int n = t >> 6, d = t & 63;
    float acc = UR[(size_t)n * DIMV + d];
    for (int k = 0; k < KNB; ++k) {
        int nb = g[n * KNB + k];
        acc += w[n * KNB + k] * UR[(size_t)nb * DIMV + d];
    }
    RES[(size_t)n * DIMV + d] = acc;
}
__global__ void k_scores(const float* __restrict__ RES, const int* __restrict__ un,
                         const int* __restrict__ pn, const int* __restrict__ nn,
                         float* __restrict__ out) {
    int gw = (blockIdx.x * blockDim.x + threadIdx.x) >> 6;
    int lane = threadIdx.x & 63;
    if (gw >= NB) return;
    int u = un[gw], p = pn[gw], ng = nn[gw];
    float uv = RES[(size_t)u * DIMV + lane];
    float ps = uv * RES[(size_t)p * DIMV + lane];
    float ns = uv * RES[(size_t)ng * DIMV + lane];
    for (int o = 32; o > 0; o >>= 1) {
        ps += __shfl_xor(ps, o);
        ns += __shfl_xor(ns, o);
    }
    if (lane == 0) { out[gw] = ps; out[NB + gw] = ns; }
}

extern "C" void kernel_launch(void* const* d_in, const int* in_sizes, int n_in,
                              void* d_out, int out_size, void* d_ws, size_t ws_size,
                              hipStream_t stream) {
    const int*   un    = (const int*)d_in[0];
    const int*   pn    = (const int*)d_in[1];
    const int*   ngn   = (const int*)d_in[2];
    const int*   ug    = (const int*)d_in[3];
    const int*   eidx  = (const int*)d_in[4];
    const float* uwm   = (const float*)d_in[5];
    const float* feats[3] = { (const float*)d_in[6], (const float*)d_in[7], (const float*)d_in[8] };
    const float* prefs[3] = { (const float*)d_in[9], (const float*)d_in[10], (const float*)d_in[11] };
    const float* W1[3] = { (const float*)d_in[12], (const float*)d_in[16], (const float*)d_in[20] };
    const float* b1[3] = { (const float*)d_in[13], (const float*)d_in[17], (const float*)d_in[21] };
    const float* W2[3] = { (const float*)d_in[14], (const float*)d_in[18], (const float*)d_in[22] };
    const float* b2[3] = { (const float*)d_in[15], (const float*)d_in[19], (const float*)d_in[23] };
    const float* wu    = (const float*)d_in[24];
    float* out = (float*)d_out;

    const int* esrc = eidx;
    const int* edst = eidx + NE;

    // ---- workspace ----
    char* ws = (char*)d_ws;
    size_t off = 0;
    auto alloc = [&](size_t bytes) { void* p = ws + off; off = (off + bytes + 255) & ~(size_t)255; return p; };
    unsigned* deg    = (unsigned*)alloc(NN * 4);
    float*    dinv   = (float*)alloc(NN * 4);
    int*      rowptr = (int*)alloc((NN + 1) * 4);
    int*      bsum   = (int*)alloc(NCH * 4);
    int*      bscan  = (int*)alloc(NCH * 4);
    int2*     csr    = (int2*)alloc((size_t)NE * 8);
    float*    X      = (float*)alloc((size_t)NN * XW * 4);
    short*    Xb     = (short*)alloc((size_t)NN * XW * 2);
    char* region2 = (char*)alloc((size_t)3 * MPAD * HIDW * 2);
    float* RES = (float*)region2;
    float* UR  = (float*)(region2 + (size_t)NN * DIMV * 4 + 40960);
    short* Hb  = (short*)(region2 + (size_t)NN * DIMV * 4 + 40960 + (size_t)NUSER * DIMV * 4);
    short* w1b = (short*)alloc((size_t)256 * 1280 * 2);
    short* w1s[3] = { w1b, w1b + 256 * 1024, w1b + 256 * (1024 + 128) };
    short* w2b = (short*)alloc((size_t)3 * 64 * HIDW * 2);
    short* w2s[3] = { w2b, w2b + 64 * HIDW, w2b + 2 * 64 * HIDW };

    // ---- 1. convert weights fp32->bf16 (tiny) ----
    CvtArgs ca;
    ca.src[0] = W1[0]; ca.src[1] = W1[1]; ca.src[2] = W1[2];
    ca.src[3] = W2[0]; ca.src[4] = W2[1]; ca.src[5] = W2[2];
    ca.dst[0] = w1s[0]; ca.dst[1] = w1s[1]; ca.dst[2] = w1s[2];
    ca.dst[3] = w2s[0]; ca.dst[4] = w2s[1]; ca.dst[5] = w2s[2];
    k_convert<<<(CVT8_TOTAL + 255) / 256, 256, 0, stream>>>(ca);

    // ---- 2. CSR build ----
    hipMemsetAsync(deg, 0, NN * 4, stream);
    k_deg<<<(NE + 255) / 256, 256, 0, stream>>>(esrc, deg);
    k_dinv<<<(NN + 255) / 256, 256, 0, stream>>>(deg, dinv);
    k_bsum<<<NCH, 256, 0, stream>>>(deg, bsum);
    k_bscan<<<1, 256, 0, stream>>>(bsum, bscan);
    k_rowptr<<<NCH, 256, 0, stream>>>(deg, bscan, rowptr);
    hipMemsetAsync(deg, 0, NN * 4, stream);
    k_fill<<<(NE + 255) / 256, 256, 0, stream>>>(esrc, edst, dinv, rowptr, deg, csr);

    // ---- 3. FUSED gemm1+gemm2+l2norm (BM=64, BN=256, A read once) ----
    G12Args g12;
    for (int m = 0; m < 3; ++m) {
        g12.A[m] = feats[m]; g12.W1[m] = w1s[m]; g12.b1[m] = b1[m];
        g12.W2[m] = w2s[m];  g12.b2[m] = b2[m];
    }
    g12.K[0] = 1024; g12.K[1] = 128; g12.K[2] = 128;
    g12.Ksrc[0] = 1024; g12.Ksrc[1] = 128; g12.Ksrc[2] = 100;
    gemm12_mfma<<<dim3(MPAD / 64, 1, 3), 256, 0, stream>>>(g12, X, Xb);
    k_users_norm<<<(NUSER * 3 * 64 + 255) / 256, 256, 0, stream>>>(prefs[0], prefs[1], prefs[2], X, Xb);

    // ---- 4. conv1: Hb = bf16(A * X) ----
    k_spmm<0><<<(NN + 3) / 4, 256, 0, stream>>>(rowptr, csr, Xb, nullptr, nullptr, Hb);

    // ---- 5. conv2: X(=REP) = X + Hb + A * Hb ----
    k_spmm<1><<<(NN + 3) / 4, 256, 0, stream>>>(rowptr, csr, Hb, X, X, nullptr);

    // ---- 6. combine / usergraph / scores ----
    k_combine<<<(NN * DIMV + 255) / 256, 256, 0, stream>>>(X, wu, UR, RES);
    k_usergraph<<<(NUSER * DIMV + 255) / 256, 256, 0, stream>>>(UR, ug, uwm, RES);
    k_scores<<<(NB * 64 + 255) / 256, 256, 0, stream>>>(RES, un, pn, ngn, out);
}

// Round 13
// 339.272 us; speedup vs baseline: 1.1907x; 1.0076x over previous
//
#include <hip/hip_runtime.h>
#include <hip/hip_bf16.h>
#include <math.h>

#define NUSER 30000
#define NITEM 30000
#define NN    60000
#define NE    1000000
#define DIMV  64
#define XW    192
#define HIDW  256
#define NB    2048
#define KNB   10
#define MPAD  30080
#define NCH   235      // ceil(NN/256)

typedef __attribute__((ext_vector_type(8))) short bf16x8;
typedef __attribute__((ext_vector_type(4))) float f32x4;

__device__ __forceinline__ short f2bf(float f) {
    union { float f; unsigned u; } v; v.f = f;
    unsigned r = v.u + 0x7fff + ((v.u >> 16) & 1);
    return (short)(r >> 16);
}
__device__ __forceinline__ float bflo(unsigned v) { return __int_as_float(v << 16); }
__device__ __forceinline__ float bfhi(unsigned v) { return __int_as_float(v & 0xffff0000u); }
__device__ __forceinline__ unsigned pack2(float a, float b) {
    return (unsigned)(unsigned short)f2bf(a) | ((unsigned)(unsigned short)f2bf(b) << 16);
}
__device__ __forceinline__ void async16(void* lds, const void* g) {
    __builtin_amdgcn_global_load_lds(
        (const __attribute__((address_space(1))) unsigned*)g,
        (__attribute__((address_space(3))) unsigned*)lds, 16, 0, 0);
}

// ================= degree / CSR =================
__global__ void k_deg(const int* __restrict__ src, unsigned* __restrict__ deg) {
    int e = blockIdx.x * blockDim.x + threadIdx.x;
    if (e < NE) atomicAdd(&deg[src[e]], 1u);
}
__global__ void k_dinv(const unsigned* __restrict__ deg, float* __restrict__ dinv) {
    int i = blockIdx.x * blockDim.x + threadIdx.x;
    if (i < NN) { unsigned d = deg[i]; dinv[i] = d ? rsqrtf((float)d) : 0.f; }
}
__global__ __launch_bounds__(256)
void k_bsum(const unsigned* __restrict__ deg, int* __restrict__ bsum) {
    __shared__ int red[4];
    int g = blockIdx.x * 256 + threadIdx.x;
    int v = (g < NN) ? (int)deg[g] : 0;
    for (int o = 32; o > 0; o >>= 1) v += __shfl_down(v, o);
    int lane = threadIdx.x & 63, wave = threadIdx.x >> 6;
    if (lane == 0) red[wave] = v;
    __syncthreads();
    if (threadIdx.x == 0) bsum[blockIdx.x] = red[0] + red[1] + red[2] + red[3];
}
__global__ __launch_bounds__(256)
void k_bscan(const int* __restrict__ bsum, int* __restrict__ bscan) {
    __shared__ int s[256];
    int t = threadIdx.x;
    int v = (t < NCH) ? bsum[t] : 0;
    s[t] = v;
    __syncthreads();
    for (int o = 1; o < 256; o <<= 1) {
        int u = (t >= o) ? s[t - o] : 0;
        __syncthreads();
        s[t] += u;
        __syncthreads();
    }
    if (t < NCH) bscan[t] = s[t] - v;
}
__global__ __launch_bounds__(256)
void k_rowptr(const unsigned* __restrict__ deg, const int* __restrict__ bscan,
              int* __restrict__ rowptr) {
    __shared__ int s[256];
    int g = blockIdx.x * 256 + threadIdx.x, t = threadIdx.x;
    int v = (g < NN) ? (int)deg[g] : 0;
    s[t] = v;
    __syncthreads();
    for (int o = 1; o < 256; o <<= 1) {
        int u = (t >= o) ? s[t - o] : 0;
        __syncthreads();
        s[t] += u;
        __syncthreads();
    }
    int base = bscan[blockIdx.x];
    if (g < NN) rowptr[g] = base + s[t] - v;
    if (g == NN - 1) rowptr[NN] = base + s[t];
}
__global__ void k_fill(const int* __restrict__ src, const int* __restrict__ dst,
                       const float* __restrict__ dinv, const int* __restrict__ rowptr,
                       unsigned* __restrict__ cursor, int2* __restrict__ csr) {
    int e = blockIdx.x * blockDim.x + threadIdx.x;
    if (e >= NE) return;
    int s = src[e], d = dst[e];
    int pos = (int)atomicAdd(&cursor[d], 1u);
    int2 ew;
    ew.x = s;
    ew.y = __float_as_int(dinv[s] * dinv[d]);
    csr[rowptr[d] + pos] = ew;
}

// ============ fp32 -> bf16 convert (weights only) ============
struct CvtArgs { const float* src[6]; short* dst[6]; };
__constant__ __device__ const int C8PRE[7]  = {0,32768,36864,40960,43008,45056,47104};
__constant__ __device__ const int C8SH[6]   = {7,4,4,5,5,5};
__constant__ __device__ const int C8COLS[6] = {1024,128,100,256,256,256};
__constant__ __device__ const int C8ROWS[6] = {256,256,256,64,64,64};
#define CVT8_TOTAL 47104

__global__ __launch_bounds__(256)
void k_convert(CvtArgs a) {
    int cid = blockIdx.x * 256 + threadIdx.x;
    if (cid >= CVT8_TOTAL) return;
    int j = 0;
    while (cid >= C8PRE[j + 1]) ++j;
    int local = cid - C8PRE[j];
    int sh = C8SH[j];
    int r = local >> sh;
    int col = (local & ((1 << sh) - 1)) * 8;
    int cols = C8COLS[j];
    bf16x8 o = (bf16x8)0;
    if (r < C8ROWS[j]) {
        const float* s = a.src[j] + (size_t)r * cols + col;
        if (col + 8 <= cols) {
            float4 f0 = *(const float4*)s;
            float4 f1 = *(const float4*)(s + 4);
            o[0] = f2bf(f0.x); o[1] = f2bf(f0.y); o[2] = f2bf(f0.z); o[3] = f2bf(f0.w);
            o[4] = f2bf(f1.x); o[5] = f2bf(f1.y); o[6] = f2bf(f1.z); o[7] = f2bf(f1.w);
        } else {
            #pragma unroll
            for (int q = 0; q < 8; ++q)
                if (col + q < cols) o[q] = f2bf(s[q]);
        }
    }
    *(bf16x8*)(a.dst[j] + ((size_t)r << (sh + 3)) + col) = o;
}

// ================= LDS helpers =================
__device__ __forceinline__ bf16x8 ldfrag(const short* lds, int row, int kbyte) {
    int off = (row * 128 + kbyte) ^ ((row & 7) << 4);
    return *(const bf16x8*)((const char*)lds + off);
}
__device__ __forceinline__ bf16x8 ldfrag512(const short* lds, int row, int kbyte) {
    int off = (row * 512 + kbyte) ^ ((row & 7) << 4);
    return *(const bf16x8*)((const char*)lds + off);
}
// 512-thread staging: chunk c -> LDS bytes c*16, global slot pre-inverse-swizzled
#define STAGE_TILE512(SMEM, BASEPTR, LDK, ROWOFF, K0, NITERS)                       \
    _Pragma("unroll")                                                                \
    for (int i_ = 0; i_ < (NITERS); ++i_) {                                          \
        int c_ = i_ * 512 + tid;                                                     \
        int r_ = c_ >> 3, slot_ = c_ & 7;                                            \
        int ss_ = slot_ ^ (r_ & 7);                                                  \
        const char* gp_ = (const char*)((BASEPTR) + (size_t)((ROWOFF) + r_) * (LDK)  \
                                        + (K0)) + ss_ * 16;                          \
        async16(&(SMEM)[c_ * 8], gp_);                                               \
    }

// ====== FUSED GEMM12, 512 threads (8 waves): BM=64, BN=256, A read once ======
struct G12Args { const float* A[3]; const short* W1[3]; const float* b1[3];
                 const short* W2[3]; const float* b2[3]; int K[3]; int Ksrc[3]; };
__global__ __launch_bounds__(512)
void gemm12_mfma(G12Args g, float* __restrict__ X, short* __restrict__ Xb) {
    __shared__ __align__(16) short sA[64 * 64];        // 8 KB
    __shared__ __align__(16) short sB[256 * 64];       // 32 KB; reused as 64x256 hidden
    short* sHid = sB;
    int m = blockIdx.z;
    int K  = g.K[m];
    int Ks = g.Ksrc[m];
    const float* A  = g.A[m];
    const short* W1 = g.W1[m];
    int tid = threadIdx.x;
    int lane = tid & 63, wave = tid >> 6;
    int wr2 = wave & 1, wc2 = wave >> 1;               // 2 row-halves x 4 col-quarters
    int lane15 = lane & 15, lhi = lane >> 4;
    int row0 = blockIdx.x * 64;
    // A staging: thread -> (row = tid>>3, 8-col chunk = tid&7)
    int srow = tid >> 3, sc8 = tid & 7;
    int grow_s = row0 + srow;
    bool rowok = grow_s < NITEM;
    const float* arow = A + (size_t)grow_s * Ks + sc8 * 8;
    int nt = K >> 6;
    float4 f[2];
    auto loadA = [&](int t) {
        int k0 = t * 64;
        int gk = k0 + sc8 * 8;
        if (rowok && gk + 8 <= Ks) {
            f[0] = *(const float4*)(arow + k0);
            f[1] = *(const float4*)(arow + k0 + 4);
        } else {
            #pragma unroll
            for (int q = 0; q < 2; ++q) {
                float4 z = make_float4(0.f, 0.f, 0.f, 0.f);
                if (rowok) {
                    int c = gk + q * 4;
                    if (c + 4 <= Ks) {
                        z = *(const float4*)(arow + k0 + q * 4);
                    } else {
                        if (c + 0 < Ks) z.x = arow[k0 + q * 4 + 0];
                        if (c + 1 < Ks) z.y = arow[k0 + q * 4 + 1];
                        if (c + 2 < Ks) z.z = arow[k0 + q * 4 + 2];
                        if (c + 3 < Ks) z.w = arow[k0 + q * 4 + 3];
                    }
                }
                f[q] = z;
            }
        }
    };
    loadA(0);
    f32x4 acc[2][4] = {};
    for (int t = 0; t < nt; ++t) {
        // A regs -> bf16 -> one swizzled ds_write per thread
        {
            bf16x8 o;
            o[0] = f2bf(f[0].x); o[1] = f2bf(f[0].y); o[2] = f2bf(f[0].z); o[3] = f2bf(f[0].w);
            o[4] = f2bf(f[1].x); o[5] = f2bf(f[1].y); o[6] = f2bf(f[1].z); o[7] = f2bf(f[1].w);
            int off = (srow * 128 + sc8 * 16) ^ ((srow & 7) << 4);
            *(bf16x8*)((char*)sA + off) = o;
        }
        STAGE_TILE512(sB, W1, K, 0, t * 64, 4)
        __syncthreads();
        if (t + 1 < nt) loadA(t + 1);    // prefetch next A tile; overlaps MFMA
        #pragma unroll
        for (int ks = 0; ks < 2; ++ks) {
            int kb = ks * 64 + lhi * 16;
            bf16x8 a[2], b[4];
            #pragma unroll
            for (int mi = 0; mi < 2; ++mi) a[mi] = ldfrag(sA, wr2 * 32 + mi * 16 + lane15, kb);
            #pragma unroll
            for (int ni = 0; ni < 4; ++ni) b[ni] = ldfrag(sB, wc2 * 64 + ni * 16 + lane15, kb);
            #pragma unroll
            for (int mi = 0; mi < 2; ++mi)
                #pragma unroll
                for (int ni = 0; ni < 4; ++ni)
                    acc[mi][ni] = __builtin_amdgcn_mfma_f32_16x16x32_bf16(a[mi], b[ni], acc[mi][ni], 0, 0, 0);
        }
        __syncthreads();
    }
    // ---- bridge: bias1 + lrelu -> bf16 -> sHid (64 x 256, 512B stride, swizzled) ----
    const float* b1 = g.b1[m];
    #pragma unroll
    for (int mi = 0; mi < 2; ++mi) {
        int rh0 = wr2 * 32 + mi * 16 + lhi * 4;
        #pragma unroll
        for (int ni = 0; ni < 4; ++ni) {
            int ch = wc2 * 64 + ni * 16 + lane15;
            float bv = b1[ch];
            #pragma unroll
            for (int r = 0; r < 4; ++r) {
                float v = acc[mi][ni][r] + bv;
                v = v > 0.f ? v : 0.01f * v;
                int rh = rh0 + r;
                int off = (rh * 512 + ch * 2) ^ ((rh & 7) << 4);
                *(short*)((char*)sHid + off) = f2bf(v);
            }
        }
    }
    __syncthreads();
    // ---- phase2 (waves 0-3): out(64x64) = hidden(64x256) * W2^T ----
    if (wave < 4) {
        const short* W2 = g.W2[m];
        const short* bp2 = W2 + (size_t)lane15 * HIDW + lhi * 8;
        f32x4 acc2[4] = {};
        #pragma unroll
        for (int k0 = 0; k0 < HIDW; k0 += 32) {
            bf16x8 a2 = ldfrag512(sHid, wave * 16 + lane15, k0 * 2 + lhi * 16);
            #pragma unroll
            for (int ni = 0; ni < 4; ++ni) {
                bf16x8 b2 = *(const bf16x8*)(bp2 + (size_t)ni * 16 * HIDW + k0);
                acc2[ni] = __builtin_amdgcn_mfma_f32_16x16x32_bf16(a2, b2, acc2[ni], 0, 0, 0);
            }
        }
        const float* b2 = g.b2[m];
        float v2[4][4];
        float sumsq[4] = {};
        #pragma unroll
        for (int ni = 0; ni < 4; ++ni) {
            float bv = b2[ni * 16 + lane15];
            #pragma unroll
            for (int r = 0; r < 4; ++r) {
                float x = acc2[ni][r] + bv;
                v2[ni][r] = x;
                sumsq[r] += x * x;
            }
        }
        #pragma unroll
        for (int r = 0; r < 4; ++r) {
            float s = sumsq[r];
            s += __shfl_xor(s, 1); s += __shfl_xor(s, 2);
            s += __shfl_xor(s, 4); s += __shfl_xor(s, 8);
            sumsq[r] = 1.f / fmaxf(sqrtf(s), 1e-12f);
        }
        int grow0 = row0 + wave * 16 + lhi * 4;
        #pragma unroll
        for (int r = 0; r < 4; ++r) {
            int grow = grow0 + r;
            if (grow < NITEM) {
                float sc = sumsq[r];
                size_t o = (size_t)(NUSER + grow) * XW + m * DIMV;
                #pragma unroll
                for (int ni = 0; ni < 4; ++ni) {
                    float val = v2[ni][r] * sc;
                    X[o + ni * 16 + lane15] = val;
                    Xb[o + ni * 16 + lane15] = f2bf(val);
                }
            }
        }
    }
}

// ================= user rows =================
__global__ void k_users_norm(const float* __restrict__ vp, const float* __restrict__ ap,
                             const float* __restrict__ tp, float* __restrict__ X,
                             short* __restrict__ Xb) {
    int gw = (blockIdx.x * blockDim.x + threadIdx.x) >> 6;
    int lane = threadIdx.x & 63;
    if (gw >= NUSER * 3) return;
    int u = gw / 3, m = gw % 3;
    const float* p = (m == 0) ? vp : (m == 1) ? ap : tp;
    float v = p[(size_t)u * DIMV + lane];
    float s = v * v;
    for (int o = 32; o > 0; o >>= 1) s += __shfl_xor(s, o);
    float sc = 1.f / fmaxf(sqrtf(s), 1e-12f);
    size_t o = (size_t)u * XW + m * DIMV + lane;
    float val = v * sc;
    X[o] = val;
    Xb[o] = f2bf(val);
}

// ================= gather SpMM, readlane SGPR bases =================
template<int MODE>
__global__ __launch_bounds__(256)
void k_spmm(const int* __restrict__ rowptr, const int2* __restrict__ csr,
            const short* __restrict__ INB, const float* __restrict__ Xf,
            float* __restrict__ OUTf, short* __restrict__ OUTB) {
    int n = blockIdx.x * 4 + (threadIdx.x >> 6);
    int l = threadIdx.x & 63;
    if (n >= NN) return;
    int lo = rowptr[n], hi = rowptr[n + 1];
    int lc = l < 48 ? l : 47;
    float f0 = 0.f, f1 = 0.f, f2 = 0.f, f3 = 0.f;
    for (int base = lo; base < hi; base += 64) {
        int idx = base + l;
        int2 e = (idx < hi) ? csr[idx] : make_int2(0, 0);
        int m = hi - base; if (m > 64) m = 64;
        int j = 0;
        for (; j + 4 <= m; j += 4) {
            int s0 = __builtin_amdgcn_readlane(e.x, j + 0);
            int s1 = __builtin_amdgcn_readlane(e.x, j + 1);
            int s2 = __builtin_amdgcn_readlane(e.x, j + 2);
            int s3 = __builtin_amdgcn_readlane(e.x, j + 3);
            float w0 = __int_as_float(__builtin_amdgcn_readlane(e.y, j + 0));
            float w1 = __int_as_float(__builtin_amdgcn_readlane(e.y, j + 1));
            float w2 = __int_as_float(__builtin_amdgcn_readlane(e.y, j + 2));
            float w3 = __int_as_float(__builtin_amdgcn_readlane(e.y, j + 3));
            uint2 v0 = ((const uint2*)(INB + (size_t)s0 * XW))[lc];
            uint2 v1 = ((const uint2*)(INB + (size_t)s1 * XW))[lc];
            uint2 v2 = ((const uint2*)(INB + (size_t)s2 * XW))[lc];
            uint2 v3 = ((const uint2*)(INB + (size_t)s3 * XW))[lc];
            f0 += w0 * bflo(v0.x); f1 += w0 * bfhi(v0.x);
            f2 += w0 * bflo(v0.y); f3 += w0 * bfhi(v0.y);
            f0 += w1 * bflo(v1.x); f1 += w1 * bfhi(v1.x);
            f2 += w1 * bflo(v1.y); f3 += w1 * bfhi(v1.y);
            f0 += w2 * bflo(v2.x); f1 += w2 * bfhi(v2.x);
            f2 += w2 * bflo(v2.y); f3 += w2 * bfhi(v2.y);
            f0 += w3 * bflo(v3.x); f1 += w3 * bfhi(v3.x);
            f2 += w3 * bflo(v3.y); f3 += w3 * bfhi(v3.y);
        }
        for (; j < m; ++j) {
            int s0 = __builtin_amdgcn_readlane(e.x, j);
            float w0 = __int_as_float(__builtin_amdgcn_readlane(e.y, j));
            uint2 v0 = ((const uint2*)(INB + (size_t)s0 * XW))[lc];
            f0 += w0 * bflo(v0.x); f1 += w0 * bfhi(v0.x);
            f2 += w0 * bflo(v0.y); f3 += w0 * bfhi(v0.y);
        }
    }
    if (MODE == 1) {
        float4 xv = ((const float4*)(Xf + (size_t)n * XW))[lc];
        uint2 hb = ((const uint2*)(INB + (size_t)n * XW))[lc];
        f0 += xv.x + bflo(hb.x); f1 += xv.y + bfhi(hb.x);
        f2 += xv.z + bflo(hb.y); f3 += xv.w + bfhi(hb.y);
    }
    if (l < 48) {
        if (MODE == 0) {
            uint2 ob;
            ob.x = pack2(f0, f1);
            ob.y = pack2(f2, f3);
            ((uint2*)(OUTB + (size_t)n * XW))[l] = ob;
        } else {
            ((float4*)(OUTf + (size_t)n * XW))[l] = make_float4(f0, f1, f2, f3);
        }
    }
}

// ================= combine / usergraph / scores =================
__global__ void k_combine(const float* __restrict__ REP, const float* __restrict__ wu,
                          float* __restrict__ UR, float* __restrict__ RES) {
    int t = blockIdx.x * blockDim.x + threadIdx.x;
    if (t >= NN * DIMV) return;
    int n = t >> 6, d = t & 63;
    const float* r = REP + (size_t)n * XW;
    float r0 = r[d], r1 = r[DIMV + d], r2 = r[2 * DIMV + d];
    if (n < NUSER) {
        float w0 = wu[n * 3 + 0], w1 = wu[n * 3 + 1], w2 = wu[n * 3 + 2];
        UR[(size_t)n * DIMV + d] = r0 * w0 + r1 * w1 + r2 * w2;
    } else {
        RES[(size_t)n * DIMV + d] = (r0 + r1 + r2) * (1.f / 3.f);
    }
}
__global__ void k_usergraph(const float* __restrict__ UR, const int* __restrict__ g,
                            const float* __restrict__ w, float* __restrict__ RES) {
    int t = blockIdx.x * blockDim.x + threadIdx.x;
    if (t >= NUSER * DIMV) return;
    int n = t >> 6, d = t & 63;
    float acc = UR[(size_t)n * DIMV + d];
    for (int k = 0; k < KNB; ++k) {
        int nb = g[n * KNB + k];
        acc += w[n * KNB + k] * UR[(size_t)nb * DIMV + d];
    }
    RES[(size_t)n * DIMV + d] = acc;
}
__global__ void k_scores(const float* __restrict__ RES, const int* __restrict__ un,
                         const int* __restrict__ pn, const int* __restrict__ nn,
                         float* __restrict__ out) {
    int gw = (blockIdx.x * blockDim.x + threadIdx.x) >> 6;
    int lane = threadIdx.x & 63;
    if (gw >= NB) return;
    int u = un[gw], p = pn[gw], ng = nn[gw];
    float uv = RES[(size_t)u * DIMV + lane];
    float ps = uv * RES[(size_t)p * DIMV + lane];
    float ns = uv * RES[(size_t)ng * DIMV + lane];
    for (int o = 32; o > 0; o >>= 1) {
        ps += __shfl_xor(ps, o);
        ns += __shfl_xor(ns, o);
    }
    if (lane == 0) { out[gw] = ps; out[NB + gw] = ns; }
}

extern "C" void kernel_launch(void* const* d_in, const int* in_sizes, int n_in,
                              void* d_out, int out_size, void* d_ws, size_t ws_size,
                              hipStream_t stream) {
    const int*   un    = (const int*)d_in[0];
    const int*   pn    = (const int*)d_in[1];
    const int*   ngn   = (const int*)d_in[2];
    const int*   ug    = (const int*)d_in[3];
    const int*   eidx  = (const int*)d_in[4];
    const float* uwm   = (const float*)d_in[5];
    const float* feats[3] = { (const float*)d_in[6], (const float*)d_in[7], (const float*)d_in[8] };
    const float* prefs[3] = { (const float*)d_in[9], (const float*)d_in[10], (const float*)d_in[11] };
    const float* W1[3] = { (const float*)d_in[12], (const float*)d_in[16], (const float*)d_in[20] };
    const float* b1[3] = { (const float*)d_in[13], (const float*)d_in[17], (const float*)d_in[21] };
    const float* W2[3] = { (const float*)d_in[14], (const float*)d_in[18], (const float*)d_in[22] };
    const float* b2[3] = { (const float*)d_in[15], (const float*)d_in[19], (const float*)d_in[23] };
    const float* wu    = (const float*)d_in[24];
    float* out = (float*)d_out;

    const int* esrc = eidx;
    const int* edst = eidx + NE;

    // ---- workspace ----
    char* ws = (char*)d_ws;
    size_t off = 0;
    auto alloc = [&](size_t bytes) { void* p = ws + off; off = (off + bytes + 255) & ~(size_t)255; return p; };
    unsigned* deg    = (unsigned*)alloc(NN * 4);
    float*    dinv   = (float*)alloc(NN * 4);
    int*      rowptr = (int*)alloc((NN + 1) * 4);
    int*      bsum   = (int*)alloc(NCH * 4);
    int*      bscan  = (int*)alloc(NCH * 4);
    int2*     csr    = (int2*)alloc((size_t)NE * 8);
    float*    X      = (float*)alloc((size_t)NN * XW * 4);
    short*    Xb     = (short*)alloc((size_t)NN * XW * 2);
    char* region2 = (char*)alloc((size_t)3 * MPAD * HIDW * 2);
    float* RES = (float*)region2;
    float* UR  = (float*)(region2 + (size_t)NN * DIMV * 4 + 40960);
    short* Hb  = (short*)(region2 + (size_t)NN * DIMV * 4 + 40960 + (size_t)NUSER * DIMV * 4);
    short* w1b = (short*)alloc((size_t)256 * 1280 * 2);
    short* w1s[3] = { w1b, w1b + 256 * 1024, w1b + 256 * (1024 + 128) };
    short* w2b = (short*)alloc((size_t)3 * 64 * HIDW * 2);
    short* w2s[3] = { w2b, w2b + 64 * HIDW, w2b + 2 * 64 * HIDW };

    // ---- 1. convert weights fp32->bf16 (tiny) ----
    CvtArgs ca;
    ca.src[0] = W1[0]; ca.src[1] = W1[1]; ca.src[2] = W1[2];
    ca.src[3] = W2[0]; ca.src[4] = W2[1]; ca.src[5] = W2[2];
    ca.dst[0] = w1s[0]; ca.dst[1] = w1s[1]; ca.dst[2] = w1s[2];
    ca.dst[3] = w2s[0]; ca.dst[4] = w2s[1]; ca.dst[5] = w2s[2];
    k_convert<<<(CVT8_TOTAL + 255) / 256, 256, 0, stream>>>(ca);

    // ---- 2. CSR build ----
    hipMemsetAsync(deg, 0, NN * 4, stream);
    k_deg<<<(NE + 255) / 256, 256, 0, stream>>>(esrc, deg);
    k_dinv<<<(NN + 255) / 256, 256, 0, stream>>>(deg, dinv);
    k_bsum<<<NCH, 256, 0, stream>>>(deg, bsum);
    k_bscan<<<1, 256, 0, stream>>>(bsum, bscan);
    k_rowptr<<<NCH, 256, 0, stream>>>(deg, bscan, rowptr);
    hipMemsetAsync(deg, 0, NN * 4, stream);
    k_fill<<<(NE + 255) / 256, 256, 0, stream>>>(esrc, edst, dinv, rowptr, deg, csr);

    // ---- 3. FUSED gemm1+gemm2+l2norm, 512 threads (8 waves) ----
    G12Args g12;
    for (int m = 0; m < 3; ++m) {
        g12.A[m] = feats[m]; g12.W1[m] = w1s[m]; g12.b1[m] = b1[m];
        g12.W2[m] = w2s[m];  g12.b2[m] = b2[m];
    }
    g12.K[0] = 1024; g12.K[1] = 128; g12.K[2] = 128;
    g12.Ksrc[0] = 1024; g12.Ksrc[1] = 128; g12.Ksrc[2] = 100;
    gemm12_mfma<<<dim3(MPAD / 64, 1, 3), 512, 0, stream>>>(g12, X, Xb);
    k_users_norm<<<(NUSER * 3 * 64 + 255) / 256, 256, 0, stream>>>(prefs[0], prefs[1], prefs[2], X, Xb);

    // ---- 4. conv1: Hb = bf16(A * X) ----
    k_spmm<0><<<(NN + 3) / 4, 256, 0, stream>>>(rowptr, csr, Xb, nullptr, nullptr, Hb);

    // ---- 5. conv2: X(=REP) = X + Hb + A * Hb ----
    k_spmm<1><<<(NN + 3) / 4, 256, 0, stream>>>(rowptr, csr, Hb, X, X, nullptr);

    // ---- 6. combine / usergraph / scores ----
    k_combine<<<(NN * DIMV + 255) / 256, 256, 0, stream>>>(X, wu, UR, RES);
    k_usergraph<<<(NUSER * DIMV + 255) / 256, 256, 0, stream>>>(UR, ug, uwm, RES);
    k_scores<<<(NB * 64 + 255) / 256, 256, 0, stream>>>(RES, un, pn, ngn, out);
}

// Round 14
// 327.090 us; speedup vs baseline: 1.2350x; 1.0372x over previous
//
#include <hip/hip_runtime.h>
#include <hip/hip_bf16.h>
#include <math.h>

#define NUSER 30000
#define NITEM 30000
#define NN    60000
#define NE    1000000
#define DIMV  64
#define XW    192
#define HIDW  256
#define NB    2048
#define KNB   10
#define MPAD  30080
#define NCH   235      // ceil(NN/256)

typedef __attribute__((ext_vector_type(8))) short bf16x8;
typedef __attribute__((ext_vector_type(4))) float f32x4;

__device__ __forceinline__ short f2bf(float f) {
    union { float f; unsigned u; } v; v.f = f;
    unsigned r = v.u + 0x7fff + ((v.u >> 16) & 1);
    return (short)(r >> 16);
}
__device__ __forceinline__ float bflo(unsigned v) { return __int_as_float(v << 16); }
__device__ __forceinline__ float bfhi(unsigned v) { return __int_as_float(v & 0xffff0000u); }
__device__ __forceinline__ unsigned pack2(float a, float b) {
    return (unsigned)(unsigned short)f2bf(a) | ((unsigned)(unsigned short)f2bf(b) << 16);
}
__device__ __forceinline__ void async16(void* lds, const void* g) {
    __builtin_amdgcn_global_load_lds(
        (const __attribute__((address_space(1))) unsigned*)g,
        (__attribute__((address_space(3))) unsigned*)lds, 16, 0, 0);
}

// ================= degree / CSR =================
__global__ void k_deg(const int* __restrict__ src, unsigned* __restrict__ deg) {
    int e = blockIdx.x * blockDim.x + threadIdx.x;
    if (e < NE) atomicAdd(&deg[src[e]], 1u);
}
__global__ void k_dinv(const unsigned* __restrict__ deg, float* __restrict__ dinv) {
    int i = blockIdx.x * blockDim.x + threadIdx.x;
    if (i < NN) { unsigned d = deg[i]; dinv[i] = d ? rsqrtf((float)d) : 0.f; }
}
__global__ __launch_bounds__(256)
void k_bsum(const unsigned* __restrict__ deg, int* __restrict__ bsum) {
    __shared__ int red[4];
    int g = blockIdx.x * 256 + threadIdx.x;
    int v = (g < NN) ? (int)deg[g] : 0;
    for (int o = 32; o > 0; o >>= 1) v += __shfl_down(v, o);
    int lane = threadIdx.x & 63, wave = threadIdx.x >> 6;
    if (lane == 0) red[wave] = v;
    __syncthreads();
    if (threadIdx.x == 0) bsum[blockIdx.x] = red[0] + red[1] + red[2] + red[3];
}
__global__ __launch_bounds__(256)
void k_bscan(const int* __restrict__ bsum, int* __restrict__ bscan) {
    __shared__ int s[256];
    int t = threadIdx.x;
    int v = (t < NCH) ? bsum[t] : 0;
    s[t] = v;
    __syncthreads();
    for (int o = 1; o < 256; o <<= 1) {
        int u = (t >= o) ? s[t - o] : 0;
        __syncthreads();
        s[t] += u;
        __syncthreads();
    }
    if (t < NCH) bscan[t] = s[t] - v;
}
__global__ __launch_bounds__(256)
void k_rowptr(const unsigned* __restrict__ deg, const int* __restrict__ bscan,
              int* __restrict__ rowptr) {
    __shared__ int s[256];
    int g = blockIdx.x * 256 + threadIdx.x, t = threadIdx.x;
    int v = (g < NN) ? (int)deg[g] : 0;
    s[t] = v;
    __syncthreads();
    for (int o = 1; o < 256; o <<= 1) {
        int u = (t >= o) ? s[t - o] : 0;
        __syncthreads();
        s[t] += u;
        __syncthreads();
    }
    int base = bscan[blockIdx.x];
    if (g < NN) rowptr[g] = base + s[t] - v;
    if (g == NN - 1) rowptr[NN] = base + s[t];
}
__global__ void k_fill(const int* __restrict__ src, const int* __restrict__ dst,
                       const float* __restrict__ dinv, const int* __restrict__ rowptr,
                       unsigned* __restrict__ cursor, int2* __restrict__ csr) {
    int e = blockIdx.x * blockDim.x + threadIdx.x;
    if (e >= NE) return;
    int s = src[e], d = dst[e];
    int pos = (int)atomicAdd(&cursor[d], 1u);
    int2 ew;
    ew.x = s;
    ew.y = __float_as_int(dinv[s] * dinv[d]);
    csr[rowptr[d] + pos] = ew;
}

// ============ fp32 -> bf16 convert (weights only) ============
struct CvtArgs { const float* src[6]; short* dst[6]; };
__constant__ __device__ const int C8PRE[7]  = {0,32768,36864,40960,43008,45056,47104};
__constant__ __device__ const int C8SH[6]   = {7,4,4,5,5,5};
__constant__ __device__ const int C8COLS[6] = {1024,128,100,256,256,256};
__constant__ __device__ const int C8ROWS[6] = {256,256,256,64,64,64};
#define CVT8_TOTAL 47104

__global__ __launch_bounds__(256)
void k_convert(CvtArgs a) {
    int cid = blockIdx.x * 256 + threadIdx.x;
    if (cid >= CVT8_TOTAL) return;
    int j = 0;
    while (cid >= C8PRE[j + 1]) ++j;
    int local = cid - C8PRE[j];
    int sh = C8SH[j];
    int r = local >> sh;
    int col = (local & ((1 << sh) - 1)) * 8;
    int cols = C8COLS[j];
    bf16x8 o = (bf16x8)0;
    if (r < C8ROWS[j]) {
        const float* s = a.src[j] + (size_t)r * cols + col;
        if (col + 8 <= cols) {
            float4 f0 = *(const float4*)s;
            float4 f1 = *(const float4*)(s + 4);
            o[0] = f2bf(f0.x); o[1] = f2bf(f0.y); o[2] = f2bf(f0.z); o[3] = f2bf(f0.w);
            o[4] = f2bf(f1.x); o[5] = f2bf(f1.y); o[6] = f2bf(f1.z); o[7] = f2bf(f1.w);
        } else {
            #pragma unroll
            for (int q = 0; q < 8; ++q)
                if (col + q < cols) o[q] = f2bf(s[q]);
        }
    }
    *(bf16x8*)(a.dst[j] + ((size_t)r << (sh + 3)) + col) = o;
}

// ================= LDS helpers =================
__device__ __forceinline__ bf16x8 ldfrag(const short* lds, int row, int kbyte) {
    int off = (row * 128 + kbyte) ^ ((row & 7) << 4);
    return *(const bf16x8*)((const char*)lds + off);
}
__device__ __forceinline__ bf16x8 ldfrag512(const short* lds, int row, int kbyte) {
    int off = (row * 512 + kbyte) ^ ((row & 7) << 4);
    return *(const bf16x8*)((const char*)lds + off);
}
#define STAGE_TILE512(SMEM, BASEPTR, LDK, ROWOFF, K0, NITERS)                       \
    _Pragma("unroll")                                                                \
    for (int i_ = 0; i_ < (NITERS); ++i_) {                                          \
        int c_ = i_ * 512 + tid;                                                     \
        int r_ = c_ >> 3, slot_ = c_ & 7;                                            \
        int ss_ = slot_ ^ (r_ & 7);                                                  \
        const char* gp_ = (const char*)((BASEPTR) + (size_t)((ROWOFF) + r_) * (LDK)  \
                                        + (K0)) + ss_ * 16;                          \
        async16(&(SMEM)[c_ * 8], gp_);                                               \
    }

// ====== FUSED GEMM12, 512 threads: A staged as RAW FP32 via global_load_lds ======
// Phase1: lrelu(A*W1^T+b1) -> LDS hidden. Phase2: hidden*W2^T+b2 -> l2norm -> X/Xb.
// A fragments converted fp32->bf16 in-register with v_cvt_pk_bf16_f32 (4 instr/frag).
struct G12Args { const float* A[3]; const short* W1[3]; const float* b1[3];
                 const short* W2[3]; const float* b2[3]; int K[3]; int Ksrc[3]; };
__global__ __launch_bounds__(512)
void gemm12_mfma(G12Args g, float* __restrict__ X, short* __restrict__ Xb) {
    __shared__ __align__(16) float sAf[64 * 64];       // 16 KB fp32 A tile (swizzled)
    __shared__ __align__(16) short sB[256 * 64];       // 32 KB bf16 B; reused as hidden
    short* sHid = sB;
    int m = blockIdx.z;
    int K  = g.K[m];          // padded loop K (1024 / 128 / 128)
    int Ks = g.Ksrc[m];       // true fp32 source cols (1024 / 128 / 100)
    const float* A  = g.A[m];
    const short* W1 = g.W1[m];
    int tid = threadIdx.x;
    int lane = tid & 63, wave = tid >> 6;
    int wr2 = wave & 1, wc2 = wave >> 1;               // 2 row-halves x 4 col-quarters
    int lane15 = lane & 15, lhi = lane >> 4;
    int row0 = blockIdx.x * 64;
    int nt = K >> 6;
    f32x4 acc[2][4] = {};
    for (int t = 0; t < nt; ++t) {
        int k0 = t * 64;
        // ---- A: fp32 global_load_lds, 2 chunks/thread, inverse-swizzled source ----
        #pragma unroll
        for (int i_ = 0; i_ < 2; ++i_) {
            int c_ = i_ * 512 + tid;              // 1024 chunks of 16B
            int r_ = c_ >> 4, slot = c_ & 15;     // 16 chunks (64 fp32) per row
            int ss = slot ^ (r_ & 7);
            int grow = row0 + r_;
            if (grow >= NITEM) grow = NITEM - 1;  // pad rows duplicate last row
            int col = k0 + ss * 4;
            if (col + 4 > Ks) col = 0;            // garbage-safe: W1 pad cols are zero
            async16(&sAf[c_ * 4], A + (size_t)grow * Ks + col);
        }
        // ---- B: bf16 global_load_lds, 4 chunks/thread ----
        STAGE_TILE512(sB, W1, K, 0, k0, 4)
        __syncthreads();
        #pragma unroll
        for (int ks = 0; ks < 2; ++ks) {
            bf16x8 a[2], b[4];
            #pragma unroll
            for (int mi = 0; mi < 2; ++mi) {
                int row = wr2 * 32 + mi * 16 + lane15;
                int cb = (ks * 32 + lhi * 8) * 4;      // byte col within row (32B aligned)
                int base = row * 256;
                int sw = (row & 7) << 4;
                f32x4 lo = *(const f32x4*)((const char*)sAf + ((base + cb) ^ sw));
                f32x4 hi = *(const f32x4*)((const char*)sAf + ((base + cb + 16) ^ sw));
                unsigned p0, p1, p2, p3;
                asm("v_cvt_pk_bf16_f32 %0, %1, %2" : "=v"(p0) : "v"(lo.x), "v"(lo.y));
                asm("v_cvt_pk_bf16_f32 %0, %1, %2" : "=v"(p1) : "v"(lo.z), "v"(lo.w));
                asm("v_cvt_pk_bf16_f32 %0, %1, %2" : "=v"(p2) : "v"(hi.x), "v"(hi.y));
                asm("v_cvt_pk_bf16_f32 %0, %1, %2" : "=v"(p3) : "v"(hi.z), "v"(hi.w));
                union { unsigned u[4]; bf16x8 v; } cvt;
                cvt.u[0] = p0; cvt.u[1] = p1; cvt.u[2] = p2; cvt.u[3] = p3;
                a[mi] = cvt.v;
            }
            int kb = ks * 64 + lhi * 16;
            #pragma unroll
            for (int ni = 0; ni < 4; ++ni) b[ni] = ldfrag(sB, wc2 * 64 + ni * 16 + lane15, kb);
            #pragma unroll
            for (int mi = 0; mi < 2; ++mi)
                #pragma unroll
                for (int ni = 0; ni < 4; ++ni)
                    acc[mi][ni] = __builtin_amdgcn_mfma_f32_16x16x32_bf16(a[mi], b[ni], acc[mi][ni], 0, 0, 0);
        }
        __syncthreads();
    }
    // ---- bridge: bias1 + lrelu -> bf16 -> sHid (64 x 256, 512B stride, swizzled) ----
    const float* b1 = g.b1[m];
    #pragma unroll
    for (int mi = 0; mi < 2; ++mi) {
        int rh0 = wr2 * 32 + mi * 16 + lhi * 4;
        #pragma unroll
        for (int ni = 0; ni < 4; ++ni) {
            int ch = wc2 * 64 + ni * 16 + lane15;
            float bv = b1[ch];
            #pragma unroll
            for (int r = 0; r < 4; ++r) {
                float v = acc[mi][ni][r] + bv;
                v = v > 0.f ? v : 0.01f * v;
                int rh = rh0 + r;
                int off = (rh * 512 + ch * 2) ^ ((rh & 7) << 4);
                *(short*)((char*)sHid + off) = f2bf(v);
            }
        }
    }
    __syncthreads();
    // ---- phase2 (waves 0-3): out(64x64) = hidden(64x256) * W2^T ----
    if (wave < 4) {
        const short* W2 = g.W2[m];
        const short* bp2 = W2 + (size_t)lane15 * HIDW + lhi * 8;
        f32x4 acc2[4] = {};
        #pragma unroll
        for (int k0 = 0; k0 < HIDW; k0 += 32) {
            bf16x8 a2 = ldfrag512(sHid, wave * 16 + lane15, k0 * 2 + lhi * 16);
            #pragma unroll
            for (int ni = 0; ni < 4; ++ni) {
                bf16x8 b2 = *(const bf16x8*)(bp2 + (size_t)ni * 16 * HIDW + k0);
                acc2[ni] = __builtin_amdgcn_mfma_f32_16x16x32_bf16(a2, b2, acc2[ni], 0, 0, 0);
            }
        }
        const float* b2 = g.b2[m];
        float v2[4][4];
        float sumsq[4] = {};
        #pragma unroll
        for (int ni = 0; ni < 4; ++ni) {
            float bv = b2[ni * 16 + lane15];
            #pragma unroll
            for (int r = 0; r < 4; ++r) {
                float x = acc2[ni][r] + bv;
                v2[ni][r] = x;
                sumsq[r] += x * x;
            }
        }
        #pragma unroll
        for (int r = 0; r < 4; ++r) {
            float s = sumsq[r];
            s += __shfl_xor(s, 1); s += __shfl_xor(s, 2);
            s += __shfl_xor(s, 4); s += __shfl_xor(s, 8);
            sumsq[r] = 1.f / fmaxf(sqrtf(s), 1e-12f);
        }
        int grow0 = row0 + wave * 16 + lhi * 4;
        #pragma unroll
        for (int r = 0; r < 4; ++r) {
            int grow = grow0 + r;
            if (grow < NITEM) {
                float sc = sumsq[r];
                size_t o = (size_t)(NUSER + grow) * XW + m * DIMV;
                #pragma unroll
                for (int ni = 0; ni < 4; ++ni) {
                    float val = v2[ni][r] * sc;
                    X[o + ni * 16 + lane15] = val;
                    Xb[o + ni * 16 + lane15] = f2bf(val);
                }
            }
        }
    }
}

// ================= user rows =================
__global__ void k_users_norm(const float* __restrict__ vp, const float* __restrict__ ap,
                             const float* __restrict__ tp, float* __restrict__ X,
                             short* __restrict__ Xb) {
    int gw = (blockIdx.x * blockDim.x + threadIdx.x) >> 6;
    int lane = threadIdx.x & 63;
    if (gw >= NUSER * 3) return;
    int u = gw / 3, m = gw % 3;
    const float* p = (m == 0) ? vp : (m == 1) ? ap : tp;
    float v = p[(size_t)u * DIMV + lane];
    float s = v * v;
    for (int o = 32; o > 0; o >>= 1) s += __shfl_xor(s, o);
    float sc = 1.f / fmaxf(sqrtf(s), 1e-12f);
    size_t o = (size_t)u * XW + m * DIMV + lane;
    float val = v * sc;
    X[o] = val;
    Xb[o] = f2bf(val);
}

// ================= gather SpMM, readlane SGPR bases =================
template<int MODE>
__global__ __launch_bounds__(256)
void k_spmm(const int* __restrict__ rowptr, const int2* __restrict__ csr,
            const short* __restrict__ INB, const float* __restrict__ Xf,
            float* __restrict__ OUTf, short* __restrict__ OUTB) {
    int n = blockIdx.x * 4 + (threadIdx.x >> 6);
    int l = threadIdx.x & 63;
    if (n >= NN) return;
    int lo = rowptr[n], hi = rowptr[n + 1];
    int lc = l < 48 ? l : 47;
    float f0 = 0.f, f1 = 0.f, f2 = 0.f, f3 = 0.f;
    for (int base = lo; base < hi; base += 64) {
        int idx = base + l;
        int2 e = (idx < hi) ? csr[idx] : make_int2(0, 0);
        int m = hi - base; if (m > 64) m = 64;
        int j = 0;
        for (; j + 4 <= m; j += 4) {
            int s0 = __builtin_amdgcn_readlane(e.x, j + 0);
            int s1 = __builtin_amdgcn_readlane(e.x, j + 1);
            int s2 = __builtin_amdgcn_readlane(e.x, j + 2);
            int s3 = __builtin_amdgcn_readlane(e.x, j + 3);
            float w0 = __int_as_float(__builtin_amdgcn_readlane(e.y, j + 0));
            float w1 = __int_as_float(__builtin_amdgcn_readlane(e.y, j + 1));
            float w2 = __int_as_float(__builtin_amdgcn_readlane(e.y, j + 2));
            float w3 = __int_as_float(__builtin_amdgcn_readlane(e.y, j + 3));
            uint2 v0 = ((const uint2*)(INB + (size_t)s0 * XW))[lc];
            uint2 v1 = ((const uint2*)(INB + (size_t)s1 * XW))[lc];
            uint2 v2 = ((const uint2*)(INB + (size_t)s2 * XW))[lc];
            uint2 v3 = ((const uint2*)(INB + (size_t)s3 * XW))[lc];
            f0 += w0 * bflo(v0.x); f1 += w0 * bfhi(v0.x);
            f2 += w0 * bflo(v0.y); f3 += w0 * bfhi(v0.y);
            f0 += w1 * bflo(v1.x); f1 += w1 * bfhi(v1.x);
            f2 += w1 * bflo(v1.y); f3 += w1 * bfhi(v1.y);
            f0 += w2 * bflo(v2.x); f1 += w2 * bfhi(v2.x);
            f2 += w2 * bflo(v2.y); f3 += w2 * bfhi(v2.y);
            f0 += w3 * bflo(v3.x); f1 += w3 * bfhi(v3.x);
            f2 += w3 * bflo(v3.y); f3 += w3 * bfhi(v3.y);
        }
        for (; j < m; ++j) {
            int s0 = __builtin_amdgcn_readlane(e.x, j);
            float w0 = __int_as_float(__builtin_amdgcn_readlane(e.y, j));
            uint2 v0 = ((const uint2*)(INB + (size_t)s0 * XW))[lc];
            f0 += w0 * bflo(v0.x); f1 += w0 * bfhi(v0.x);
            f2 += w0 * bflo(v0.y); f3 += w0 * bfhi(v0.y);
        }
    }
    if (MODE == 1) {
        float4 xv = ((const float4*)(Xf + (size_t)n * XW))[lc];
        uint2 hb = ((const uint2*)(INB + (size_t)n * XW))[lc];
        f0 += xv.x + bflo(hb.x); f1 += xv.y + bfhi(hb.x);
        f2 += xv.z + bflo(hb.y); f3 += xv.w + bfhi(hb.y);
    }
    if (l < 48) {
        if (MODE == 0) {
            uint2 ob;
            ob.x = pack2(f0, f1);
            ob.y = pack2(f2, f3);
            ((uint2*)(OUTB + (size_t)n * XW))[l] = ob;
        } else {
            ((float4*)(OUTf + (size_t)n * XW))[l] = make_float4(f0, f1, f2, f3);
        }
    }
}

// ================= combine / usergraph / scores =================
__global__ void k_combine(const float* __restrict__ REP, const float* __restrict__ wu,
                          float* __restrict__ UR, float* __restrict__ RES) {
    int t = blockIdx.x * blockDim.x + threadIdx.x;
    if (t >= NN * DIMV) return;
    int n = t >> 6, d = t & 63;
    const float* r = REP + (size_t)n * XW;
    float r0 = r[d], r1 = r[DIMV + d], r2 = r[2 * DIMV + d];
    if (n < NUSER) {
        float w0 = wu[n * 3 + 0], w1 = wu[n * 3 + 1], w2 = wu[n * 3 + 2];
        UR[(size_t)n * DIMV + d] = r0 * w0 + r1 * w1 + r2 * w2;
    } else {
        RES[(size_t)n * DIMV + d] = (r0 + r1 + r2) * (1.f / 3.f);
    }
}
__global__ void k_usergraph(const float* __restrict__ UR, const int* __restrict__ g,
                            const float* __restrict__ w, float* __restrict__ RES) {
    int t = blockIdx.x * blockDim.x + threadIdx.x;
    if (t >= NUSER * DIMV) return;
    int n = t >> 6, d = t & 63;
    float acc = UR[(size_t)n * DIMV + d];
    for (int k = 0; k < KNB; ++k) {
        int nb = g[n * KNB + k];
        acc += w[n * KNB + k] * UR[(size_t)nb * DIMV + d];
    }
    RES[(size_t)n * DIMV + d] = acc;
}
__global__ void k_scores(const float* __restrict__ RES, const int* __restrict__ un,
                         const int* __restrict__ pn, const int* __restrict__ nn,
                         float* __restrict__ out) {
    int gw = (blockIdx.x * blockDim.x + threadIdx.x) >> 6;
    int lane = threadIdx.x & 63;
    if (gw >= NB) return;
    int u = un[gw], p = pn[gw], ng = nn[gw];
    float uv = RES[(size_t)u * DIMV + lane];
    float ps = uv * RES[(size_t)p * DIMV + lane];
    float ns = uv * RES[(size_t)ng * DIMV + lane];
    for (int o = 32; o > 0; o >>= 1) {
        ps += __shfl_xor(ps, o);
        ns += __shfl_xor(ns, o);
    }
    if (lane == 0) { out[gw] = ps; out[NB + gw] = ns; }
}

extern "C" void kernel_launch(void* const* d_in, const int* in_sizes, int n_in,
                              void* d_out, int out_size, void* d_ws, size_t ws_size,
                              hipStream_t stream) {
    const int*   un    = (const int*)d_in[0];
    const int*   pn    = (const int*)d_in[1];
    const int*   ngn   = (const int*)d_in[2];
    const int*   ug    = (const int*)d_in[3];
    const int*   eidx  = (const int*)d_in[4];
    const float* uwm   = (const float*)d_in[5];
    const float* feats[3] = { (const float*)d_in[6], (const float*)d_in[7], (const float*)d_in[8] };
    const float* prefs[3] = { (const float*)d_in[9], (const float*)d_in[10], (const float*)d_in[11] };
    const float* W1[3] = { (const float*)d_in[12], (const float*)d_in[16], (const float*)d_in[20] };
    const float* b1[3] = { (const float*)d_in[13], (const float*)d_in[17], (const float*)d_in[21] };
    const float* W2[3] = { (const float*)d_in[14], (const float*)d_in[18], (const float*)d_in[22] };
    const float* b2[3] = { (const float*)d_in[15], (const float*)d_in[19], (const float*)d_in[23] };
    const float* wu    = (const float*)d_in[24];
    float* out = (float*)d_out;

    const int* esrc = eidx;
    const int* edst = eidx + NE;

    // ---- workspace ----
    char* ws = (char*)d_ws;
    size_t off = 0;
    auto alloc = [&](size_t bytes) { void* p = ws + off; off = (off + bytes + 255) & ~(size_t)255; return p; };
    unsigned* deg    = (unsigned*)alloc(NN * 4);
    float*    dinv   = (float*)alloc(NN * 4);
    int*      rowptr = (int*)alloc((NN + 1) * 4);
    int*      bsum   = (int*)alloc(NCH * 4);
    int*      bscan  = (int*)alloc(NCH * 4);
    int2*     csr    = (int2*)alloc((size_t)NE * 8);
    float*    X      = (float*)alloc((size_t)NN * XW * 4);
    short*    Xb     = (short*)alloc((size_t)NN * XW * 2);
    char* region2 = (char*)alloc((size_t)3 * MPAD * HIDW * 2);
    float* RES = (float*)region2;
    float* UR  = (float*)(region2 + (size_t)NN * DIMV * 4 + 40960);
    short* Hb  = (short*)(region2 + (size_t)NN * DIMV * 4 + 40960 + (size_t)NUSER * DIMV * 4);
    short* w1b = (short*)alloc((size_t)256 * 1280 * 2);
    short* w1s[3] = { w1b, w1b + 256 * 1024, w1b + 256 * (1024 + 128) };
    short* w2b = (short*)alloc((size_t)3 * 64 * HIDW * 2);
    short* w2s[3] = { w2b, w2b + 64 * HIDW, w2b + 2 * 64 * HIDW };

    // ---- 1. convert weights fp32->bf16 (tiny) ----
    CvtArgs ca;
    ca.src[0] = W1[0]; ca.src[1] = W1[1]; ca.src[2] = W1[2];
    ca.src[3] = W2[0]; ca.src[4] = W2[1]; ca.src[5] = W2[2];
    ca.dst[0] = w1s[0]; ca.dst[1] = w1s[1]; ca.dst[2] = w1s[2];
    ca.dst[3] = w2s[0]; ca.dst[4] = w2s[1]; ca.dst[5] = w2s[2];
    k_convert<<<(CVT8_TOTAL + 255) / 256, 256, 0, stream>>>(ca);

    // ---- 2. CSR build ----
    hipMemsetAsync(deg, 0, NN * 4, stream);
    k_deg<<<(NE + 255) / 256, 256, 0, stream>>>(esrc, deg);
    k_dinv<<<(NN + 255) / 256, 256, 0, stream>>>(deg, dinv);
    k_bsum<<<NCH, 256, 0, stream>>>(deg, bsum);
    k_bscan<<<1, 256, 0, stream>>>(bsum, bscan);
    k_rowptr<<<NCH, 256, 0, stream>>>(deg, bscan, rowptr);
    hipMemsetAsync(deg, 0, NN * 4, stream);
    k_fill<<<(NE + 255) / 256, 256, 0, stream>>>(esrc, edst, dinv, rowptr, deg, csr);

    // ---- 3. FUSED gemm1+gemm2+l2norm, A staged fp32 via global_load_lds ----
    G12Args g12;
    for (int m = 0; m < 3; ++m) {
        g12.A[m] = feats[m]; g12.W1[m] = w1s[m]; g12.b1[m] = b1[m];
        g12.W2[m] = w2s[m];  g12.b2[m] = b2[m];
    }
    g12.K[0] = 1024; g12.K[1] = 128; g12.K[2] = 128;
    g12.Ksrc[0] = 1024; g12.Ksrc[1] = 128; g12.Ksrc[2] = 100;
    gemm12_mfma<<<dim3(MPAD / 64, 1, 3), 512, 0, stream>>>(g12, X, Xb);
    k_users_norm<<<(NUSER * 3 * 64 + 255) / 256, 256, 0, stream>>>(prefs[0], prefs[1], prefs[2], X, Xb);

    // ---- 4. conv1: Hb = bf16(A * X) ----
    k_spmm<0><<<(NN + 3) / 4, 256, 0, stream>>>(rowptr, csr, Xb, nullptr, nullptr, Hb);

    // ---- 5. conv2: X(=REP) = X + Hb + A * Hb ----
    k_spmm<1><<<(NN + 3) / 4, 256, 0, stream>>>(rowptr, csr, Hb, X, X, nullptr);

    // ---- 6. combine / usergraph / scores ----
    k_combine<<<(NN * DIMV + 255) / 256, 256, 0, stream>>>(X, wu, UR, RES);
    k_usergraph<<<(NUSER * DIMV + 255) / 256, 256, 0, stream>>>(UR, ug, uwm, RES);
    k_scores<<<(NB * 64 + 255) / 256, 256, 0, stream>>>(RES, un, pn, ngn, out);
}